// Round 9
// baseline (490.017 us; speedup 1.0000x reference)
//
#include <hip/hip_runtime.h>
#include <hip/hip_bf16.h>

#define EMBED 1024
#define HEADS 16
#define HEAD_DIM 64
#define FFDIM 4096
#define TSEQ 2048
#define BATCH 4
#define ROWS (BATCH * TSEQ)  // 8192

typedef __bf16 bf16;
typedef __attribute__((ext_vector_type(8))) __bf16 bf16x8;
typedef __attribute__((ext_vector_type(4))) __bf16 bf16x4;
typedef __attribute__((ext_vector_type(4))) float f32x4;

typedef const __attribute__((address_space(1))) void* gvp;
typedef __attribute__((address_space(3))) void* svp;

// ---------------- weight conversion (LDS-tiled transposes, coalesced) ----------------
__global__ __launch_bounds__(256) void conv_wqkv_t(
    const float* __restrict__ Wq, const float* __restrict__ Wk,
    const float* __restrict__ Wv, bf16* __restrict__ WqkvT) {
  __shared__ bf16 t[64][72];
  int tid = threadIdx.x;
  int k0 = blockIdx.x * 64;  // c-tile
  int head = blockIdx.y;
  int which = blockIdx.z;
  const float* src = which == 0 ? Wq : which == 1 ? Wk : Wv;
  float scale = which == 0 ? 0.125f * 1.44269504088896f : 1.0f;
  src += (size_t)head * 65536;
  bf16* dst = WqkvT + ((size_t)which * 1024 + head * 64) * 1024;
#pragma unroll
  for (int i = 0; i < 4; ++i) {
    int r = i * 16 + (tid >> 4);  // c within tile
    int c = (tid & 15) * 4;       // d
    float4 v = *(const float4*)&src[(size_t)(k0 + r) * 64 + c];
    t[c + 0][r] = (bf16)(v.x * scale);
    t[c + 1][r] = (bf16)(v.y * scale);
    t[c + 2][r] = (bf16)(v.z * scale);
    t[c + 3][r] = (bf16)(v.w * scale);
  }
  __syncthreads();
#pragma unroll
  for (int i = 0; i < 2; ++i) {
    int r = i * 32 + (tid >> 3);  // d row
    int c = (tid & 7) * 8;        // c col
    bf16x8 o;
#pragma unroll
    for (int j = 0; j < 8; ++j) o[j] = t[r][c + j];
    *(bf16x8*)&dst[(size_t)r * 1024 + k0 + c] = o;
  }
}

// W [K,N] fp32 -> WT [N,K] bf16, tiled 64x64
__global__ __launch_bounds__(256) void transpose_conv(
    const float* __restrict__ W, bf16* __restrict__ WT, int K, int N) {
  __shared__ bf16 t[64][72];
  int tid = threadIdx.x;
  int n0 = blockIdx.x * 64, k0 = blockIdx.y * 64;
#pragma unroll
  for (int i = 0; i < 4; ++i) {
    int r = i * 16 + (tid >> 4);  // k
    int c = (tid & 15) * 4;       // n
    float4 v = *(const float4*)&W[(size_t)(k0 + r) * N + n0 + c];
    t[c + 0][r] = (bf16)v.x;
    t[c + 1][r] = (bf16)v.y;
    t[c + 2][r] = (bf16)v.z;
    t[c + 3][r] = (bf16)v.w;
  }
  __syncthreads();
#pragma unroll
  for (int i = 0; i < 2; ++i) {
    int r = i * 32 + (tid >> 3);  // n
    int c = (tid & 7) * 8;        // k
    bf16x8 o;
#pragma unroll
    for (int j = 0; j < 8; ++j) o[j] = t[r][c + j];
    *(bf16x8*)&WT[(size_t)(n0 + r) * K + k0 + c] = o;
  }
}

// v [B,H,T,Dh] bf16 -> vt [B,H,Dh,T] bf16, per-bh 64x64 tiles
__global__ __launch_bounds__(256) void transpose_v(const bf16* __restrict__ v,
                                                   bf16* __restrict__ vt) {
  __shared__ bf16 t[64][72];
  int bh = blockIdx.y;
  int t0 = blockIdx.x * 64;
  const bf16* src = v + (size_t)bh * 131072;
  bf16* dst = vt + (size_t)bh * 131072;
  int tid = threadIdx.x;
#pragma unroll
  for (int i = 0; i < 2; ++i) {
    int c = tid + i * 256;
    int r = c >> 3, d0 = (c & 7) * 8;
    bf16x8 vv = *(const bf16x8*)&src[(size_t)(t0 + r) * 64 + d0];
#pragma unroll
    for (int j = 0; j < 8; ++j) t[d0 + j][r] = vv[j];
  }
  __syncthreads();
#pragma unroll
  for (int i = 0; i < 2; ++i) {
    int c = tid + i * 256;
    int r = c >> 3, s0 = (c & 7) * 8;
    bf16x8 o;
#pragma unroll
    for (int j = 0; j < 8; ++j) o[j] = t[r][s0 + j];
    *(bf16x8*)&dst[(size_t)r * 2048 + t0 + s0] = o;
  }
}

// ---------------- layernorm (fp32 in -> bf16 out) ----------------
__global__ __launch_bounds__(256) void ln_kernel(
    const float* __restrict__ x, const float* __restrict__ g,
    const float* __restrict__ bta, bf16* __restrict__ out) {
  int row = blockIdx.x;
  const float* xr = x + (size_t)row * EMBED;
  float4 v = ((const float4*)xr)[threadIdx.x];
  float s1 = v.x + v.y + v.z + v.w;
  float s2 = v.x * v.x + v.y * v.y + v.z * v.z + v.w * v.w;
#pragma unroll
  for (int off = 1; off < 64; off <<= 1) {
    s1 += __shfl_xor(s1, off);
    s2 += __shfl_xor(s2, off);
  }
  __shared__ float red[8];
  int wid = threadIdx.x >> 6;
  int lane = threadIdx.x & 63;
  if (lane == 0) {
    red[wid * 2] = s1;
    red[wid * 2 + 1] = s2;
  }
  __syncthreads();
  s1 = red[0] + red[2] + red[4] + red[6];
  s2 = red[1] + red[3] + red[5] + red[7];
  float mu = s1 * (1.0f / EMBED);
  float var = s2 * (1.0f / EMBED) - mu * mu;
  float rs = rsqrtf(var + 1e-5f);
  float4 gv = ((const float4*)g)[threadIdx.x];
  float4 bv = ((const float4*)bta)[threadIdx.x];
  bf16x4 o;
  o[0] = (bf16)((v.x - mu) * rs * gv.x + bv.x);
  o[1] = (bf16)((v.y - mu) * rs * gv.y + bv.y);
  o[2] = (bf16)((v.z - mu) * rs * gv.z + bv.z);
  o[3] = (bf16)((v.w - mu) * rs * gv.w + bv.w);
  *(bf16x4*)(out + (size_t)row * EMBED + threadIdx.x * 4) = o;
}

// ---------------- 256x256 GEMM, BK=32, 3 LDS buffers, 2-phase interleave ----------------
template <int EPI>
__global__ __launch_bounds__(512, 1) void gemm256(
    const bf16* __restrict__ A, const bf16* __restrict__ BT,
    bf16* __restrict__ Cb, const float* __restrict__ bias, int M, int N,
    int K) {
  __shared__ __attribute__((aligned(16))) char lds[98304];  // 3 x (A16K + B16K)
  int gx = gridDim.x;
  int nwg = gx * gridDim.y;
  int wgid = blockIdx.y * gx + blockIdx.x;
  int cpx = nwg >> 3;
  int swz = (wgid & 7) * cpx + (wgid >> 3);
  int m0 = (swz / gx) * 256, n0 = (swz % gx) * 256;
  int tid = threadIdx.x;
  int lane = tid & 63, wid = tid >> 6;
  int lr = lane & 15, lg = lane >> 4;
  int wrM = (wid >> 2) * 128;  // wave M base: 0 or 128
  int wcN = (wid & 3) * 64;    // wave N base: 0/64/128/192
  int crow = lane >> 2;        // staging row within 16-row chunk
  int slotg = (lane & 3) ^ (crow & 3);  // inverse-swizzled global 16B slot
  int NT = K >> 5;
  size_t rb = (size_t)K * 2;  // bytes per row of A / BT

  auto stageA = [&](int t) {
    char* dst = lds + ((unsigned)t % 3u) * 32768u;
#pragma unroll
    for (int q = 0; q < 2; ++q) {
      int c = wid * 2 + q;  // chunk 0..15 (16 rows each)
      const char* srcA = (const char*)A + (size_t)(m0 + c * 16 + crow) * rb +
                         (size_t)t * 64 + slotg * 16;
      __builtin_amdgcn_global_load_lds((gvp)srcA, (svp)(dst + c * 1024), 16, 0,
                                       0);
    }
  };
  auto stageB = [&](int t) {
    char* dst = lds + ((unsigned)t % 3u) * 32768u + 16384u;
#pragma unroll
    for (int q = 0; q < 2; ++q) {
      int c = wid * 2 + q;
      const char* srcB = (const char*)BT + (size_t)(n0 + c * 16 + crow) * rb +
                         (size_t)t * 64 + slotg * 16;
      __builtin_amdgcn_global_load_lds((gvp)srcB, (svp)(dst + c * 1024), 16, 0,
                                       0);
    }
  };

  stageA(0);
  stageB(0);
  stageA(1);
  stageB(1);
  f32x4 acc[8][4] = {};
  int swcol = ((lg ^ (lr & 3)) * 16);
  for (int t = 0; t < NT; ++t) {
    if (t == NT - 1)
      asm volatile("s_waitcnt vmcnt(0)" ::: "memory");
    else
      asm volatile("s_waitcnt vmcnt(4)" ::: "memory");
    __builtin_amdgcn_s_barrier();
    __builtin_amdgcn_sched_barrier(0);
    const char* Ab = lds + ((unsigned)t % 3u) * 32768u;
    const char* Bb = Ab + 16384;
    int tn = t + 2;
    bool st = tn < NT;
    // ---- phase A ----
    bf16x8 bfr[4], afA[4], afB[4];
#pragma unroll
    for (int j = 0; j < 4; ++j)
      bfr[j] = *(const bf16x8*)(Bb + (wcN + j * 16 + lr) * 64 + swcol);
#pragma unroll
    for (int i = 0; i < 4; ++i)
      afA[i] = *(const bf16x8*)(Ab + (wrM + i * 16 + lr) * 64 + swcol);
    if (st) stageA(tn);
    __builtin_amdgcn_s_barrier();
    __builtin_amdgcn_sched_barrier(0);
    __builtin_amdgcn_s_setprio(1);
#pragma unroll
    for (int i = 0; i < 4; ++i)
#pragma unroll
      for (int j = 0; j < 4; ++j)
        acc[i][j] = __builtin_amdgcn_mfma_f32_16x16x32_bf16(afA[i], bfr[j],
                                                            acc[i][j], 0, 0, 0);
    __builtin_amdgcn_s_setprio(0);
    __builtin_amdgcn_sched_barrier(0);
    // ---- phase B ----
#pragma unroll
    for (int i = 0; i < 4; ++i)
      afB[i] = *(const bf16x8*)(Ab + (wrM + 64 + i * 16 + lr) * 64 + swcol);
    if (st) stageB(tn);
    __builtin_amdgcn_s_barrier();
    __builtin_amdgcn_sched_barrier(0);
    __builtin_amdgcn_s_setprio(1);
#pragma unroll
    for (int i = 0; i < 4; ++i)
#pragma unroll
      for (int j = 0; j < 4; ++j)
        acc[4 + i][j] = __builtin_amdgcn_mfma_f32_16x16x32_bf16(
            afB[i], bfr[j], acc[4 + i][j], 0, 0, 0);
    __builtin_amdgcn_s_setprio(0);
    __builtin_amdgcn_sched_barrier(0);
  }
#pragma unroll
  for (int i = 0; i < 8; ++i) {
#pragma unroll
    for (int j = 0; j < 4; ++j) {
#pragma unroll
      for (int r = 0; r < 4; ++r) {
        int row = m0 + wrM + i * 16 + lg * 4 + r;
        int col = n0 + wcN + j * 16 + lr;
        float v = acc[i][j][r];
        if (EPI == 0) {
          int which = col >> 10, cc = col & 1023;
          int b = row >> 11, tt = row & 2047, h = cc >> 6, d = cc & 63;
          bf16* dst = Cb + (size_t)which * 8388608;
          dst[((size_t)((b << 4) + h) * TSEQ + tt) * HEAD_DIM + d] = (bf16)v;
        } else {
          size_t o = (size_t)row * N + col;
          float u = v + bias[col];
          Cb[o] = (bf16)(u > 0.f ? u : 0.f);
        }
      }
    }
  }
}

// ---------------- GEMM (m97 structure + XCD swizzle) for N=1024 cases ----------------
// EPI 2: fp32 out = resid + bias + acc
template <int EPI>
__global__ __launch_bounds__(256) void gemm_bf16(
    const bf16* __restrict__ A, const bf16* __restrict__ BT,
    float* __restrict__ Cf, bf16* __restrict__ Cb,
    const float* __restrict__ bias, const float* __restrict__ resid, int M,
    int N, int K) {
  __shared__ __attribute__((aligned(16))) bf16 As[128 * 32];
  __shared__ __attribute__((aligned(16))) bf16 Bs[128 * 32];
  int gx = gridDim.x;
  int nwg = gx * gridDim.y;
  int wgid = blockIdx.y * gx + blockIdx.x;
  int cpx = nwg >> 3;
  int swz = (wgid & 7) * cpx + (wgid >> 3);
  int m0 = (swz / gx) * 128, n0 = (swz % gx) * 128;
  int tid = threadIdx.x;
  int lane = tid & 63, wid = tid >> 6;
  int lr = lane & 15, lg = lane >> 4;
  int wr = (wid >> 1) * 64, wc = (wid & 1) * 64;
  int srow = lane >> 2;
  int sk = (lane & 3) * 8;
  f32x4 acc[4][4] = {};
  for (int kt = 0; kt < K; kt += 32) {
#pragma unroll
    for (int i = 0; i < 2; ++i) {
      int c = wid * 2 + i;
      int row = c * 16 + srow;
      const bf16* ga = &A[(size_t)(m0 + row) * K + kt + sk];
      const bf16* gb = &BT[(size_t)(n0 + row) * K + kt + sk];
      __builtin_amdgcn_global_load_lds((gvp)(const void*)ga,
                                       (svp)(void*)&As[c * 512], 16, 0, 0);
      __builtin_amdgcn_global_load_lds((gvp)(const void*)gb,
                                       (svp)(void*)&Bs[c * 512], 16, 0, 0);
    }
    __syncthreads();
    bf16x8 af[4], bfr[4];
#pragma unroll
    for (int i = 0; i < 4; ++i) {
      af[i] = *(const bf16x8*)&As[(wr + i * 16 + lr) * 32 + lg * 8];
      bfr[i] = *(const bf16x8*)&Bs[(wc + i * 16 + lr) * 32 + lg * 8];
    }
#pragma unroll
    for (int ar = 0; ar < 4; ++ar)
#pragma unroll
      for (int br = 0; br < 4; ++br)
        acc[ar][br] = __builtin_amdgcn_mfma_f32_16x16x32_bf16(
            af[ar], bfr[br], acc[ar][br], 0, 0, 0);
    __syncthreads();
  }
#pragma unroll
  for (int ar = 0; ar < 4; ++ar) {
#pragma unroll
    for (int br = 0; br < 4; ++br) {
#pragma unroll
      for (int r = 0; r < 4; ++r) {
        int row = m0 + wr + ar * 16 + lg * 4 + r;
        int col = n0 + wc + br * 16 + lr;
        float v = acc[ar][br][r];
        size_t o = (size_t)row * N + col;
        Cf[o] = resid[o] + bias[col] + v;
      }
    }
  }
}

// ---------------- causal flash attention: chunked KV-split, fixed-shift softmax ----------
// Work item table (24 items/bh, sorted longest-first): Q>=8 split into 2 even
// KV-chunks (partials, fp32, combined by combine_attn); Q<=7 single chunk
// (writes final). Fixed-shift softmax => partials are exactly associative.
// grid (24, 64): x = item, y = bh. 1536 blocks = 6/CU (refill headroom).
__global__ __launch_bounds__(256) void attn_kernel(
    const bf16* __restrict__ q, const bf16* __restrict__ k,
    const bf16* __restrict__ vt, bf16* __restrict__ out,
    float* __restrict__ part) {
  __shared__ __attribute__((aligned(16))) bf16 Ks[64][68];
  __shared__ __attribute__((aligned(16))) bf16 Vs[64][68];
  __shared__ __attribute__((aligned(16))) bf16 Ps[4][32][68];
  constexpr int QA[24] = {15, 15, 7, 14, 14, 13, 13, 6, 12, 12, 11, 11,
                          5,  10, 10, 4, 9,  9,  8,  8, 3,  2,  1,  0};
  constexpr int J0[24] = {0, 16, 0, 0, 15, 0, 14, 0, 0, 13, 0, 12,
                          0, 0,  11, 0, 0, 10, 0, 9, 0, 0,  0, 0};
  constexpr int J1[24] = {16, 32, 16, 15, 30, 14, 28, 14, 13, 26, 12, 24,
                          12, 11, 22, 10, 10, 20, 9,  18, 8,  6,  4,  2};
  constexpr int SL[24] = {14, 15, -1, 12, 13, 10, 11, -1, 8,  9,  6,  7,
                          -1, 4,  5,  -1, 2,  3,  0,  1,  -1, -1, -1, -1};
  int item = blockIdx.x, bh = blockIdx.y;
  int Q = QA[item], j0 = J0[item], j1 = J1[item], slot = SL[item];
  int b = bh >> 4, h = bh & 15;
  const bf16* qb = q + (size_t)bh * TSEQ * HEAD_DIM;
  const bf16* kb = k + (size_t)bh * TSEQ * HEAD_DIM;
  const bf16* vb = vt + (size_t)bh * HEAD_DIM * TSEQ;
  int tid = threadIdx.x, lane = tid & 63, w = tid >> 6;
  int lr = lane & 15, lg = lane >> 4;
  int tw = Q * 128 + w * 32;
  bf16x8 aq[2][2];
#pragma unroll
  for (int rg = 0; rg < 2; ++rg)
#pragma unroll
    for (int kc = 0; kc < 2; ++kc)
      aq[rg][kc] = *(const bf16x8*)&qb[(size_t)(tw + rg * 16 + lr) * HEAD_DIM +
                                       kc * 32 + lg * 8];
  f32x4 o[2][4] = {};
  float lrow[2][4] = {};
  for (int j = j0; j < j1; ++j) {
#pragma unroll
    for (int i = 0; i < 2; ++i) {
      int c = tid + i * 256;
      int rr = c >> 3, ko = (c & 7) * 8;
      *(bf16x8*)&Ks[rr][ko] =
          *(const bf16x8*)&kb[(size_t)(j * 64 + rr) * HEAD_DIM + ko];
      *(bf16x8*)&Vs[rr][ko] =
          *(const bf16x8*)&vb[(size_t)rr * TSEQ + j * 64 + ko];
    }
    __syncthreads();
    f32x4 s[2][4] = {};
#pragma unroll
    for (int nb = 0; nb < 4; ++nb) {
#pragma unroll
      for (int kc = 0; kc < 2; ++kc) {
        bf16x8 bk = *(const bf16x8*)&Ks[nb * 16 + lr][kc * 32 + lg * 8];
        s[0][nb] = __builtin_amdgcn_mfma_f32_16x16x32_bf16(aq[0][kc], bk,
                                                           s[0][nb], 0, 0, 0);
        s[1][nb] = __builtin_amdgcn_mfma_f32_16x16x32_bf16(aq[1][kc], bk,
                                                           s[1][nb], 0, 0, 0);
      }
    }
    if (j >= 2 * Q) {
#pragma unroll
      for (int rg = 0; rg < 2; ++rg)
#pragma unroll
        for (int nb = 0; nb < 4; ++nb)
#pragma unroll
          for (int r = 0; r < 4; ++r) {
            int sg = j * 64 + nb * 16 + lr;
            int tg = tw + rg * 16 + lg * 4 + r;
            if (sg > tg) s[rg][nb][r] = -1e30f;
          }
    }
#pragma unroll
    for (int rg = 0; rg < 2; ++rg) {
      float p[4][4];
#pragma unroll
      for (int r = 0; r < 4; ++r) {
        float su = 0.f;
#pragma unroll
        for (int nb = 0; nb < 4; ++nb) {
          p[nb][r] = exp2f(s[rg][nb][r] - 8.0f);
          su += p[nb][r];
        }
#pragma unroll
        for (int off = 1; off < 16; off <<= 1) su += __shfl_xor(su, off);
        lrow[rg][r] += su;
      }
#pragma unroll
      for (int nb = 0; nb < 4; ++nb)
#pragma unroll
        for (int r = 0; r < 4; ++r)
          Ps[w][rg * 16 + lg * 4 + r][nb * 16 + lr] = (bf16)p[nb][r];
    }
#pragma unroll
    for (int kc = 0; kc < 2; ++kc) {
      bf16x8 pa0 = *(const bf16x8*)&Ps[w][lr][kc * 32 + lg * 8];
      bf16x8 pa1 = *(const bf16x8*)&Ps[w][16 + lr][kc * 32 + lg * 8];
#pragma unroll
      for (int br = 0; br < 4; ++br) {
        bf16x8 bv = *(const bf16x8*)&Vs[br * 16 + lr][kc * 32 + lg * 8];
        o[0][br] =
            __builtin_amdgcn_mfma_f32_16x16x32_bf16(pa0, bv, o[0][br], 0, 0, 0);
        o[1][br] =
            __builtin_amdgcn_mfma_f32_16x16x32_bf16(pa1, bv, o[1][br], 0, 0, 0);
      }
    }
    __syncthreads();
  }
  if (slot < 0) {
#pragma unroll
    for (int rg = 0; rg < 2; ++rg)
#pragma unroll
      for (int br = 0; br < 4; ++br)
#pragma unroll
        for (int r = 0; r < 4; ++r) {
          int t = tw + rg * 16 + lg * 4 + r;
          int d = br * 16 + lr;
          float val = o[rg][br][r] / lrow[rg][r];
          out[((size_t)(b * TSEQ) + t) * EMBED + h * HEAD_DIM + d] = (bf16)val;
        }
  } else {
    float* pb = part + ((size_t)bh * 16 + slot) * 8320;
#pragma unroll
    for (int rg = 0; rg < 2; ++rg)
#pragma unroll
      for (int br = 0; br < 4; ++br)
#pragma unroll
        for (int r = 0; r < 4; ++r) {
          int row = w * 32 + rg * 16 + lg * 4 + r;
          int d = br * 16 + lr;
          pb[row * 64 + d] = o[rg][br][r];
        }
    if (lr == 0) {
#pragma unroll
      for (int rg = 0; rg < 2; ++rg)
#pragma unroll
        for (int r = 0; r < 4; ++r)
          pb[8192 + w * 32 + rg * 16 + lg * 4 + r] = lrow[rg][r];
    }
  }
}

// combine partials for Q in 8..15: out = (oa+ob)/(la+lb)
__global__ __launch_bounds__(256) void combine_attn(
    const float* __restrict__ part, bf16* __restrict__ out) {
  int bh = blockIdx.x;
  int Q = 8 + blockIdx.y;
  int b = bh >> 4, h = bh & 15;
  const float* pa = part + ((size_t)bh * 16 + (Q - 8) * 2) * 8320;
  const float* pc = pa + 8320;
  for (int i = threadIdx.x; i < 8192; i += 256) {
    int row = i >> 6, d = i & 63;
    float l = pa[8192 + row] + pc[8192 + row];
    float v = (pa[i] + pc[i]) / l;
    int t = Q * 128 + row;
    out[((size_t)(b * TSEQ) + t) * EMBED + h * HEAD_DIM + d] = (bf16)v;
  }
}

// ---------------- launch ----------------
extern "C" void kernel_launch(void* const* d_in, const int* in_sizes, int n_in,
                              void* d_out, int out_size, void* d_ws,
                              size_t ws_size, hipStream_t stream) {
  const float* x = (const float*)d_in[0];
  const float* Wq = (const float*)d_in[1];
  const float* Wk = (const float*)d_in[2];
  const float* Wv = (const float*)d_in[3];
  const float* Wo = (const float*)d_in[4];
  const float* bo = (const float*)d_in[5];
  const float* W1 = (const float*)d_in[6];
  const float* b1 = (const float*)d_in[7];
  const float* W2 = (const float*)d_in[8];
  const float* b2 = (const float*)d_in[9];
  const float* g1 = (const float*)d_in[10];
  const float* be1 = (const float*)d_in[11];
  const float* g2 = (const float*)d_in[12];
  const float* be2 = (const float*)d_in[13];
  float* out = (float*)d_out;
  char* ws = (char*)d_ws;

  const size_t U = 16777216;  // 16 MiB
  // U0 h/vt/ff1; U1 q; U2 k; U3 vnb/ao; U4-5 x1 (fp32) AND transient attn
  // partials (consumed by combine before x1 is written); U6 h2; weights at 7U.
  bf16* h = (bf16*)(ws + 0 * U);
  bf16* qb = (bf16*)(ws + 1 * U);
  bf16* vtb = (bf16*)(ws + 0 * U);
  bf16* vnb = (bf16*)(ws + 3 * U);
  bf16* ao = (bf16*)(ws + 3 * U);
  float* x1 = (float*)(ws + 4 * U);
  float* attn_part = (float*)(ws + 4 * U);  // 64*16*8320 f32 = 32.5 MB
  bf16* h2 = (bf16*)(ws + 6 * U);
  bf16* ff1 = (bf16*)(ws + 0 * U);
  char* wbase = ws + 7 * U;
  bf16* WqkvT = (bf16*)(wbase);           // 6 MB
  bf16* WoT = (bf16*)(wbase + 6291456);   // 2 MB
  bf16* W1T = (bf16*)(wbase + 8388608);   // 8 MB
  bf16* W2T = (bf16*)(wbase + 16777216);  // 8 MB

  hipLaunchKernelGGL(conv_wqkv_t, dim3(16, 16, 3), dim3(256), 0, stream, Wq,
                     Wk, Wv, WqkvT);
  hipLaunchKernelGGL(transpose_conv, dim3(16, 16), dim3(256), 0, stream, Wo,
                     WoT, 1024, 1024);
  hipLaunchKernelGGL(transpose_conv, dim3(64, 16), dim3(256), 0, stream, W1,
                     W1T, 1024, 4096);
  hipLaunchKernelGGL(transpose_conv, dim3(16, 64), dim3(256), 0, stream, W2,
                     W2T, 4096, 1024);
  hipLaunchKernelGGL(ln_kernel, dim3(8192), dim3(256), 0, stream, x, g1, be1,
                     h);
  // fused QKV projection: 256x256 2-phase pipelined GEMM, scatter epilogue
  hipLaunchKernelGGL((gemm256<0>), dim3(12, 32), dim3(512), 0, stream, h,
                     WqkvT, qb, (const float*)nullptr, ROWS, 3072, 1024);
  // v [B,H,T,D] -> vt [B,H,D,T]
  hipLaunchKernelGGL(transpose_v, dim3(32, 64), dim3(256), 0, stream, vnb,
                     vtb);
  // attention: chunked KV-split (fixed-shift softmax => associative partials)
  hipLaunchKernelGGL(attn_kernel, dim3(24, 64), dim3(256), 0, stream, qb,
                     qb + 8388608, vtb, ao, attn_part);
  hipLaunchKernelGGL(combine_attn, dim3(64, 8), dim3(256), 0, stream,
                     attn_part, ao);
  // x1 = x + ao @ Wo + bo
  hipLaunchKernelGGL((gemm_bf16<2>), dim3(8, 64), dim3(256), 0, stream, ao,
                     WoT, x1, (bf16*)nullptr, bo, x, ROWS, 1024, 1024);
  // h2 = LN2(x1)
  hipLaunchKernelGGL(ln_kernel, dim3(8192), dim3(256), 0, stream, x1, g2, be2,
                     h2);
  // ff1 = relu(h2 @ W1 + b1): 256x256 2-phase pipelined GEMM
  hipLaunchKernelGGL((gemm256<3>), dim3(16, 32), dim3(512), 0, stream, h2, W1T,
                     ff1, b1, ROWS, 4096, 1024);
  // out = x1 + ff1 @ W2 + b2
  hipLaunchKernelGGL((gemm_bf16<2>), dim3(8, 64), dim3(256), 0, stream, ff1,
                     W2T, out, (bf16*)nullptr, b2, x1, ROWS, 1024, 4096);
}

// Round 10
// 436.751 us; speedup vs baseline: 1.1220x; 1.1220x over previous
//
#include <hip/hip_runtime.h>
#include <hip/hip_bf16.h>

#define EMBED 1024
#define HEADS 16
#define HEAD_DIM 64
#define FFDIM 4096
#define TSEQ 2048
#define BATCH 4
#define ROWS (BATCH * TSEQ)  // 8192

typedef __bf16 bf16;
typedef __attribute__((ext_vector_type(8))) __bf16 bf16x8;
typedef __attribute__((ext_vector_type(4))) __bf16 bf16x4;
typedef __attribute__((ext_vector_type(4))) float f32x4;

typedef const __attribute__((address_space(1))) void* gvp;
typedef __attribute__((address_space(3))) void* svp;

// ---------------- weight conversion (LDS-tiled transposes, coalesced) ----------------
__global__ __launch_bounds__(256) void conv_wqkv_t(
    const float* __restrict__ Wq, const float* __restrict__ Wk,
    const float* __restrict__ Wv, bf16* __restrict__ WqkvT) {
  __shared__ bf16 t[64][72];
  int tid = threadIdx.x;
  int k0 = blockIdx.x * 64;  // c-tile
  int head = blockIdx.y;
  int which = blockIdx.z;
  const float* src = which == 0 ? Wq : which == 1 ? Wk : Wv;
  float scale = which == 0 ? 0.125f * 1.44269504088896f : 1.0f;
  src += (size_t)head * 65536;
  bf16* dst = WqkvT + ((size_t)which * 1024 + head * 64) * 1024;
#pragma unroll
  for (int i = 0; i < 4; ++i) {
    int r = i * 16 + (tid >> 4);  // c within tile
    int c = (tid & 15) * 4;       // d
    float4 v = *(const float4*)&src[(size_t)(k0 + r) * 64 + c];
    t[c + 0][r] = (bf16)(v.x * scale);
    t[c + 1][r] = (bf16)(v.y * scale);
    t[c + 2][r] = (bf16)(v.z * scale);
    t[c + 3][r] = (bf16)(v.w * scale);
  }
  __syncthreads();
#pragma unroll
  for (int i = 0; i < 2; ++i) {
    int r = i * 32 + (tid >> 3);  // d row
    int c = (tid & 7) * 8;        // c col
    bf16x8 o;
#pragma unroll
    for (int j = 0; j < 8; ++j) o[j] = t[r][c + j];
    *(bf16x8*)&dst[(size_t)r * 1024 + k0 + c] = o;
  }
}

// W [K,N] fp32 -> WT [N,K] bf16, tiled 64x64
__global__ __launch_bounds__(256) void transpose_conv(
    const float* __restrict__ W, bf16* __restrict__ WT, int K, int N) {
  __shared__ bf16 t[64][72];
  int tid = threadIdx.x;
  int n0 = blockIdx.x * 64, k0 = blockIdx.y * 64;
#pragma unroll
  for (int i = 0; i < 4; ++i) {
    int r = i * 16 + (tid >> 4);  // k
    int c = (tid & 15) * 4;       // n
    float4 v = *(const float4*)&W[(size_t)(k0 + r) * N + n0 + c];
    t[c + 0][r] = (bf16)v.x;
    t[c + 1][r] = (bf16)v.y;
    t[c + 2][r] = (bf16)v.z;
    t[c + 3][r] = (bf16)v.w;
  }
  __syncthreads();
#pragma unroll
  for (int i = 0; i < 2; ++i) {
    int r = i * 32 + (tid >> 3);  // n
    int c = (tid & 7) * 8;        // k
    bf16x8 o;
#pragma unroll
    for (int j = 0; j < 8; ++j) o[j] = t[r][c + j];
    *(bf16x8*)&WT[(size_t)(n0 + r) * K + k0 + c] = o;
  }
}

// v [B,H,T,Dh] bf16 -> vt [B,H,Dh,T] bf16, per-bh 64x64 tiles
__global__ __launch_bounds__(256) void transpose_v(const bf16* __restrict__ v,
                                                   bf16* __restrict__ vt) {
  __shared__ bf16 t[64][72];
  int bh = blockIdx.y;
  int t0 = blockIdx.x * 64;
  const bf16* src = v + (size_t)bh * 131072;
  bf16* dst = vt + (size_t)bh * 131072;
  int tid = threadIdx.x;
#pragma unroll
  for (int i = 0; i < 2; ++i) {
    int c = tid + i * 256;
    int r = c >> 3, d0 = (c & 7) * 8;
    bf16x8 vv = *(const bf16x8*)&src[(size_t)(t0 + r) * 64 + d0];
#pragma unroll
    for (int j = 0; j < 8; ++j) t[d0 + j][r] = vv[j];
  }
  __syncthreads();
#pragma unroll
  for (int i = 0; i < 2; ++i) {
    int c = tid + i * 256;
    int r = c >> 3, s0 = (c & 7) * 8;
    bf16x8 o;
#pragma unroll
    for (int j = 0; j < 8; ++j) o[j] = t[r][s0 + j];
    *(bf16x8*)&dst[(size_t)r * 2048 + t0 + s0] = o;
  }
}

// ---------------- layernorm (fp32 in -> bf16 out) ----------------
__global__ __launch_bounds__(256) void ln_kernel(
    const float* __restrict__ x, const float* __restrict__ g,
    const float* __restrict__ bta, bf16* __restrict__ out) {
  int row = blockIdx.x;
  const float* xr = x + (size_t)row * EMBED;
  float4 v = ((const float4*)xr)[threadIdx.x];
  float s1 = v.x + v.y + v.z + v.w;
  float s2 = v.x * v.x + v.y * v.y + v.z * v.z + v.w * v.w;
#pragma unroll
  for (int off = 1; off < 64; off <<= 1) {
    s1 += __shfl_xor(s1, off);
    s2 += __shfl_xor(s2, off);
  }
  __shared__ float red[8];
  int wid = threadIdx.x >> 6;
  int lane = threadIdx.x & 63;
  if (lane == 0) {
    red[wid * 2] = s1;
    red[wid * 2 + 1] = s2;
  }
  __syncthreads();
  s1 = red[0] + red[2] + red[4] + red[6];
  s2 = red[1] + red[3] + red[5] + red[7];
  float mu = s1 * (1.0f / EMBED);
  float var = s2 * (1.0f / EMBED) - mu * mu;
  float rs = rsqrtf(var + 1e-5f);
  float4 gv = ((const float4*)g)[threadIdx.x];
  float4 bv = ((const float4*)bta)[threadIdx.x];
  bf16x4 o;
  o[0] = (bf16)((v.x - mu) * rs * gv.x + bv.x);
  o[1] = (bf16)((v.y - mu) * rs * gv.y + bv.y);
  o[2] = (bf16)((v.z - mu) * rs * gv.z + bv.z);
  o[3] = (bf16)((v.w - mu) * rs * gv.w + bv.w);
  *(bf16x4*)(out + (size_t)row * EMBED + threadIdx.x * 4) = o;
}

// ---------------- 256x256 GEMM, BK=32, 3 LDS buffers, 2-phase interleave ----------------
template <int EPI>
__global__ __launch_bounds__(512, 1) void gemm256(
    const bf16* __restrict__ A, const bf16* __restrict__ BT,
    bf16* __restrict__ Cb, const float* __restrict__ bias, int M, int N,
    int K) {
  __shared__ __attribute__((aligned(16))) char lds[98304];  // 3 x (A16K + B16K)
  int gx = gridDim.x;
  int nwg = gx * gridDim.y;
  int wgid = blockIdx.y * gx + blockIdx.x;
  int cpx = nwg >> 3;
  int swz = (wgid & 7) * cpx + (wgid >> 3);
  int m0 = (swz / gx) * 256, n0 = (swz % gx) * 256;
  int tid = threadIdx.x;
  int lane = tid & 63, wid = tid >> 6;
  int lr = lane & 15, lg = lane >> 4;
  int wrM = (wid >> 2) * 128;  // wave M base: 0 or 128
  int wcN = (wid & 3) * 64;    // wave N base: 0/64/128/192
  int crow = lane >> 2;        // staging row within 16-row chunk
  int slotg = (lane & 3) ^ (crow & 3);  // inverse-swizzled global 16B slot
  int NT = K >> 5;
  size_t rb = (size_t)K * 2;  // bytes per row of A / BT

  auto stageA = [&](int t) {
    char* dst = lds + ((unsigned)t % 3u) * 32768u;
#pragma unroll
    for (int q = 0; q < 2; ++q) {
      int c = wid * 2 + q;  // chunk 0..15 (16 rows each)
      const char* srcA = (const char*)A + (size_t)(m0 + c * 16 + crow) * rb +
                         (size_t)t * 64 + slotg * 16;
      __builtin_amdgcn_global_load_lds((gvp)srcA, (svp)(dst + c * 1024), 16, 0,
                                       0);
    }
  };
  auto stageB = [&](int t) {
    char* dst = lds + ((unsigned)t % 3u) * 32768u + 16384u;
#pragma unroll
    for (int q = 0; q < 2; ++q) {
      int c = wid * 2 + q;
      const char* srcB = (const char*)BT + (size_t)(n0 + c * 16 + crow) * rb +
                         (size_t)t * 64 + slotg * 16;
      __builtin_amdgcn_global_load_lds((gvp)srcB, (svp)(dst + c * 1024), 16, 0,
                                       0);
    }
  };

  stageA(0);
  stageB(0);
  stageA(1);
  stageB(1);
  f32x4 acc[8][4] = {};
  int swcol = ((lg ^ (lr & 3)) * 16);
  for (int t = 0; t < NT; ++t) {
    if (t == NT - 1)
      asm volatile("s_waitcnt vmcnt(0)" ::: "memory");
    else
      asm volatile("s_waitcnt vmcnt(4)" ::: "memory");
    __builtin_amdgcn_s_barrier();
    __builtin_amdgcn_sched_barrier(0);
    const char* Ab = lds + ((unsigned)t % 3u) * 32768u;
    const char* Bb = Ab + 16384;
    int tn = t + 2;
    bool st = tn < NT;
    // ---- phase A ----
    bf16x8 bfr[4], afA[4], afB[4];
#pragma unroll
    for (int j = 0; j < 4; ++j)
      bfr[j] = *(const bf16x8*)(Bb + (wcN + j * 16 + lr) * 64 + swcol);
#pragma unroll
    for (int i = 0; i < 4; ++i)
      afA[i] = *(const bf16x8*)(Ab + (wrM + i * 16 + lr) * 64 + swcol);
    if (st) stageA(tn);
    __builtin_amdgcn_s_barrier();
    __builtin_amdgcn_sched_barrier(0);
    __builtin_amdgcn_s_setprio(1);
#pragma unroll
    for (int i = 0; i < 4; ++i)
#pragma unroll
      for (int j = 0; j < 4; ++j)
        acc[i][j] = __builtin_amdgcn_mfma_f32_16x16x32_bf16(afA[i], bfr[j],
                                                            acc[i][j], 0, 0, 0);
    __builtin_amdgcn_s_setprio(0);
    __builtin_amdgcn_sched_barrier(0);
    // ---- phase B ----
#pragma unroll
    for (int i = 0; i < 4; ++i)
      afB[i] = *(const bf16x8*)(Ab + (wrM + 64 + i * 16 + lr) * 64 + swcol);
    if (st) stageB(tn);
    __builtin_amdgcn_s_barrier();
    __builtin_amdgcn_sched_barrier(0);
    __builtin_amdgcn_s_setprio(1);
#pragma unroll
    for (int i = 0; i < 4; ++i)
#pragma unroll
      for (int j = 0; j < 4; ++j)
        acc[4 + i][j] = __builtin_amdgcn_mfma_f32_16x16x32_bf16(
            afB[i], bfr[j], acc[4 + i][j], 0, 0, 0);
    __builtin_amdgcn_s_setprio(0);
    __builtin_amdgcn_sched_barrier(0);
  }
#pragma unroll
  for (int i = 0; i < 8; ++i) {
#pragma unroll
    for (int j = 0; j < 4; ++j) {
#pragma unroll
      for (int r = 0; r < 4; ++r) {
        int row = m0 + wrM + i * 16 + lg * 4 + r;
        int col = n0 + wcN + j * 16 + lr;
        float v = acc[i][j][r];
        if (EPI == 0) {
          int which = col >> 10, cc = col & 1023;
          int b = row >> 11, tt = row & 2047, h = cc >> 6, d = cc & 63;
          bf16* dst = Cb + (size_t)which * 8388608;
          dst[((size_t)((b << 4) + h) * TSEQ + tt) * HEAD_DIM + d] = (bf16)v;
        } else {
          size_t o = (size_t)row * N + col;
          float u = v + bias[col];
          Cb[o] = (bf16)(u > 0.f ? u : 0.f);
        }
      }
    }
  }
}

// ---------------- GEMM (m97 structure + XCD swizzle) for N=1024 cases ----------------
// EPI 2: fp32 out = resid + bias + acc
template <int EPI>
__global__ __launch_bounds__(256) void gemm_bf16(
    const bf16* __restrict__ A, const bf16* __restrict__ BT,
    float* __restrict__ Cf, bf16* __restrict__ Cb,
    const float* __restrict__ bias, const float* __restrict__ resid, int M,
    int N, int K) {
  __shared__ __attribute__((aligned(16))) bf16 As[128 * 32];
  __shared__ __attribute__((aligned(16))) bf16 Bs[128 * 32];
  int gx = gridDim.x;
  int nwg = gx * gridDim.y;
  int wgid = blockIdx.y * gx + blockIdx.x;
  int cpx = nwg >> 3;
  int swz = (wgid & 7) * cpx + (wgid >> 3);
  int m0 = (swz / gx) * 128, n0 = (swz % gx) * 128;
  int tid = threadIdx.x;
  int lane = tid & 63, wid = tid >> 6;
  int lr = lane & 15, lg = lane >> 4;
  int wr = (wid >> 1) * 64, wc = (wid & 1) * 64;
  int srow = lane >> 2;
  int sk = (lane & 3) * 8;
  f32x4 acc[4][4] = {};
  for (int kt = 0; kt < K; kt += 32) {
#pragma unroll
    for (int i = 0; i < 2; ++i) {
      int c = wid * 2 + i;
      int row = c * 16 + srow;
      const bf16* ga = &A[(size_t)(m0 + row) * K + kt + sk];
      const bf16* gb = &BT[(size_t)(n0 + row) * K + kt + sk];
      __builtin_amdgcn_global_load_lds((gvp)(const void*)ga,
                                       (svp)(void*)&As[c * 512], 16, 0, 0);
      __builtin_amdgcn_global_load_lds((gvp)(const void*)gb,
                                       (svp)(void*)&Bs[c * 512], 16, 0, 0);
    }
    __syncthreads();
    bf16x8 af[4], bfr[4];
#pragma unroll
    for (int i = 0; i < 4; ++i) {
      af[i] = *(const bf16x8*)&As[(wr + i * 16 + lr) * 32 + lg * 8];
      bfr[i] = *(const bf16x8*)&Bs[(wc + i * 16 + lr) * 32 + lg * 8];
    }
#pragma unroll
    for (int ar = 0; ar < 4; ++ar)
#pragma unroll
      for (int br = 0; br < 4; ++br)
        acc[ar][br] = __builtin_amdgcn_mfma_f32_16x16x32_bf16(
            af[ar], bfr[br], acc[ar][br], 0, 0, 0);
    __syncthreads();
  }
#pragma unroll
  for (int ar = 0; ar < 4; ++ar) {
#pragma unroll
    for (int br = 0; br < 4; ++br) {
#pragma unroll
      for (int r = 0; r < 4; ++r) {
        int row = m0 + wr + ar * 16 + lg * 4 + r;
        int col = n0 + wc + br * 16 + lr;
        float v = acc[ar][br][r];
        size_t o = (size_t)row * N + col;
        Cf[o] = resid[o] + bias[col] + v;
      }
    }
  }
}

// ---------------- causal flash attention: QBLK=128, rg=2, fixed-shift softmax,
// deferred row-sum, 32KB XOR-swizzled LDS (5 blocks/CU) ----------------------------
// grid (64, 16) x 256: x = bh (XCD L2 locality), y -> Q = 15-y (longest first)
__global__ __launch_bounds__(256) void attn_kernel(
    const bf16* __restrict__ q, const bf16* __restrict__ k,
    const bf16* __restrict__ vt, bf16* __restrict__ out) {
  // Ks 8KB | Vs 8KB | Ps 16KB (4KB/wave), all XOR-swizzled: byte ^= (row&7)<<4
  __shared__ __attribute__((aligned(16))) char ldsK[8192];
  __shared__ __attribute__((aligned(16))) char ldsV[8192];
  __shared__ __attribute__((aligned(16))) char ldsP[16384];
  int bh = blockIdx.x;
  int b = bh >> 4, h = bh & 15;
  const bf16* qb = q + (size_t)bh * TSEQ * HEAD_DIM;
  const bf16* kb = k + (size_t)bh * TSEQ * HEAD_DIM;
  const bf16* vb = vt + (size_t)bh * HEAD_DIM * TSEQ;
  int tid = threadIdx.x, lane = tid & 63, w = tid >> 6;
  int lr = lane & 15, lg = lane >> 4;
  int Q = 15 - blockIdx.y;     // supertile of 128 rows; longest job first
  int tw = Q * 128 + w * 32;   // wave's base row
  // staging indices: 512 slots of 16B (64 rows x 8 col-slots)
  int srow0 = tid >> 3;          // rows 0..31 (i=0), +32 (i=1)
  int scol = (tid & 7) * 16;     // byte col
  bf16x8 aq[2][2];
#pragma unroll
  for (int rg = 0; rg < 2; ++rg)
#pragma unroll
    for (int kc = 0; kc < 2; ++kc)
      aq[rg][kc] = *(const bf16x8*)&qb[(size_t)(tw + rg * 16 + lr) * HEAD_DIM +
                                       kc * 32 + lg * 8];
  f32x4 o[2][4] = {};
  float sacc[2][4] = {};
  char* myP = ldsP + w * 4096;
  int nj = 2 * Q + 2;
  for (int j = 0; j < nj; ++j) {
#pragma unroll
    for (int i = 0; i < 2; ++i) {
      int rr = srow0 + i * 32;
      int sw = scol ^ ((rr & 7) << 4);
      *(bf16x8*)(ldsK + rr * 128 + sw) =
          *(const bf16x8*)&kb[(size_t)(j * 64 + rr) * HEAD_DIM + (scol >> 1)];
      *(bf16x8*)(ldsV + rr * 128 + sw) =
          *(const bf16x8*)&vb[(size_t)rr * TSEQ + j * 64 + (scol >> 1)];
    }
    __syncthreads();
    f32x4 s[2][4] = {};
#pragma unroll
    for (int nb = 0; nb < 4; ++nb) {
      int rowK = nb * 16 + lr;
#pragma unroll
      for (int kc = 0; kc < 2; ++kc) {
        int cb = (kc * 64 + lg * 16) ^ ((rowK & 7) << 4);
        bf16x8 bk = *(const bf16x8*)(ldsK + rowK * 128 + cb);
        s[0][nb] = __builtin_amdgcn_mfma_f32_16x16x32_bf16(aq[0][kc], bk,
                                                           s[0][nb], 0, 0, 0);
        s[1][nb] = __builtin_amdgcn_mfma_f32_16x16x32_bf16(aq[1][kc], bk,
                                                           s[1][nb], 0, 0, 0);
      }
    }
    if (j >= 2 * Q) {  // boundary tiles: causal mask
#pragma unroll
      for (int rg = 0; rg < 2; ++rg)
#pragma unroll
        for (int nb = 0; nb < 4; ++nb)
#pragma unroll
          for (int r = 0; r < 4; ++r) {
            int sg = j * 64 + nb * 16 + lr;
            int tg = tw + rg * 16 + lg * 4 + r;
            if (sg > tg) s[rg][nb][r] = -1e30f;
          }
    }
#pragma unroll
    for (int rg = 0; rg < 2; ++rg) {
#pragma unroll
      for (int r = 0; r < 4; ++r) {
        int rowP = rg * 16 + lg * 4 + r;
        int swr = (rowP & 7) << 4;
        float psum = 0.f;
#pragma unroll
        for (int nb = 0; nb < 4; ++nb) {
          float p = exp2f(s[rg][nb][r] - 8.0f);
          psum += p;
          *(bf16*)(myP + rowP * 128 + (((nb * 16 + lr) * 2) ^ swr)) = (bf16)p;
        }
        sacc[rg][r] += psum;  // deferred: no per-j shuffle reduce
      }
    }
    // P is per-wave: no barrier needed between store and read
#pragma unroll
    for (int kc = 0; kc < 2; ++kc) {
      int cb0 = (kc * 64 + lg * 16) ^ ((lr & 7) << 4);
      bf16x8 pa0 = *(const bf16x8*)(myP + lr * 128 + cb0);
      bf16x8 pa1 = *(const bf16x8*)(myP + (16 + lr) * 128 + cb0);
#pragma unroll
      for (int br = 0; br < 4; ++br) {
        int rowV = br * 16 + lr;
        int cbv = (kc * 64 + lg * 16) ^ ((rowV & 7) << 4);
        bf16x8 bv = *(const bf16x8*)(ldsV + rowV * 128 + cbv);
        o[0][br] =
            __builtin_amdgcn_mfma_f32_16x16x32_bf16(pa0, bv, o[0][br], 0, 0, 0);
        o[1][br] =
            __builtin_amdgcn_mfma_f32_16x16x32_bf16(pa1, bv, o[1][br], 0, 0, 0);
      }
    }
    __syncthreads();
  }
  float lrow[2][4];
#pragma unroll
  for (int rg = 0; rg < 2; ++rg)
#pragma unroll
    for (int r = 0; r < 4; ++r) {
      float su = sacc[rg][r];
#pragma unroll
      for (int off = 1; off < 16; off <<= 1) su += __shfl_xor(su, off);
      lrow[rg][r] = su;
    }
#pragma unroll
  for (int rg = 0; rg < 2; ++rg)
#pragma unroll
    for (int br = 0; br < 4; ++br)
#pragma unroll
      for (int r = 0; r < 4; ++r) {
        int t = tw + rg * 16 + lg * 4 + r;
        int d = br * 16 + lr;
        float val = o[rg][br][r] / lrow[rg][r];
        out[((size_t)(b * TSEQ) + t) * EMBED + h * HEAD_DIM + d] = (bf16)val;
      }
}

// ---------------- launch ----------------
extern "C" void kernel_launch(void* const* d_in, const int* in_sizes, int n_in,
                              void* d_out, int out_size, void* d_ws,
                              size_t ws_size, hipStream_t stream) {
  const float* x = (const float*)d_in[0];
  const float* Wq = (const float*)d_in[1];
  const float* Wk = (const float*)d_in[2];
  const float* Wv = (const float*)d_in[3];
  const float* Wo = (const float*)d_in[4];
  const float* bo = (const float*)d_in[5];
  const float* W1 = (const float*)d_in[6];
  const float* b1 = (const float*)d_in[7];
  const float* W2 = (const float*)d_in[8];
  const float* b2 = (const float*)d_in[9];
  const float* g1 = (const float*)d_in[10];
  const float* be1 = (const float*)d_in[11];
  const float* g2 = (const float*)d_in[12];
  const float* be2 = (const float*)d_in[13];
  float* out = (float*)d_out;
  char* ws = (char*)d_ws;

  const size_t U = 16777216;  // 16 MiB
  bf16* h = (bf16*)(ws + 0 * U);
  bf16* qb = (bf16*)(ws + 1 * U);
  bf16* vtb = (bf16*)(ws + 0 * U);
  bf16* vnb = (bf16*)(ws + 3 * U);
  bf16* ao = (bf16*)(ws + 3 * U);
  float* x1 = (float*)(ws + 4 * U);
  bf16* h2 = (bf16*)(ws + 6 * U);
  bf16* ff1 = (bf16*)(ws + 0 * U);
  char* wbase = ws + 7 * U;
  bf16* WqkvT = (bf16*)(wbase);           // 6 MB
  bf16* WoT = (bf16*)(wbase + 6291456);   // 2 MB
  bf16* W1T = (bf16*)(wbase + 8388608);   // 8 MB
  bf16* W2T = (bf16*)(wbase + 16777216);  // 8 MB

  hipLaunchKernelGGL(conv_wqkv_t, dim3(16, 16, 3), dim3(256), 0, stream, Wq,
                     Wk, Wv, WqkvT);
  hipLaunchKernelGGL(transpose_conv, dim3(16, 16), dim3(256), 0, stream, Wo,
                     WoT, 1024, 1024);
  hipLaunchKernelGGL(transpose_conv, dim3(64, 16), dim3(256), 0, stream, W1,
                     W1T, 1024, 4096);
  hipLaunchKernelGGL(transpose_conv, dim3(16, 64), dim3(256), 0, stream, W2,
                     W2T, 4096, 1024);
  hipLaunchKernelGGL(ln_kernel, dim3(8192), dim3(256), 0, stream, x, g1, be1,
                     h);
  // fused QKV projection: 256x256 2-phase pipelined GEMM, scatter epilogue
  hipLaunchKernelGGL((gemm256<0>), dim3(12, 32), dim3(512), 0, stream, h,
                     WqkvT, qb, (const float*)nullptr, ROWS, 3072, 1024);
  // v [B,H,T,D] -> vt [B,H,D,T]
  hipLaunchKernelGGL(transpose_v, dim3(32, 64), dim3(256), 0, stream, vnb,
                     vtb);
  // attention (QBLK=128, rg=2, fixed-shift softmax, deferred sum, 32KB LDS)
  hipLaunchKernelGGL(attn_kernel, dim3(64, 16), dim3(256), 0, stream, qb,
                     qb + 8388608, vtb, ao);
  // x1 = x + ao @ Wo + bo
  hipLaunchKernelGGL((gemm_bf16<2>), dim3(8, 64), dim3(256), 0, stream, ao,
                     WoT, x1, (bf16*)nullptr, bo, x, ROWS, 1024, 1024);
  // h2 = LN2(x1)
  hipLaunchKernelGGL(ln_kernel, dim3(8192), dim3(256), 0, stream, x1, g2, be2,
                     h2);
  // ff1 = relu(h2 @ W1 + b1): 256x256 2-phase pipelined GEMM
  hipLaunchKernelGGL((gemm256<3>), dim3(16, 32), dim3(512), 0, stream, h2, W1T,
                     ff1, b1, ROWS, 4096, 1024);
  // out = x1 + ff1 @ W2 + b2
  hipLaunchKernelGGL((gemm_bf16<2>), dim3(8, 64), dim3(256), 0, stream, ff1,
                     W2T, out, (bf16*)nullptr, b2, x1, ROWS, 1024, 4096);
}

// Round 11
// 402.640 us; speedup vs baseline: 1.2170x; 1.0847x over previous
//
#include <hip/hip_runtime.h>
#include <hip/hip_bf16.h>

#define EMBED 1024
#define HEADS 16
#define HEAD_DIM 64
#define FFDIM 4096
#define TSEQ 2048
#define BATCH 4
#define ROWS (BATCH * TSEQ)  // 8192

typedef __bf16 bf16;
typedef __attribute__((ext_vector_type(8))) __bf16 bf16x8;
typedef __attribute__((ext_vector_type(4))) __bf16 bf16x4;
typedef __attribute__((ext_vector_type(4))) float f32x4;

typedef const __attribute__((address_space(1))) void* gvp;
typedef __attribute__((address_space(3))) void* svp;

// ---------------- weight conversion (LDS-tiled transposes, coalesced) ----------------
__global__ __launch_bounds__(256) void conv_wqkv_t(
    const float* __restrict__ Wq, const float* __restrict__ Wk,
    const float* __restrict__ Wv, bf16* __restrict__ WqkvT) {
  __shared__ bf16 t[64][72];
  int tid = threadIdx.x;
  int k0 = blockIdx.x * 64;  // c-tile
  int head = blockIdx.y;
  int which = blockIdx.z;
  const float* src = which == 0 ? Wq : which == 1 ? Wk : Wv;
  float scale = which == 0 ? 0.125f * 1.44269504088896f : 1.0f;
  src += (size_t)head * 65536;
  bf16* dst = WqkvT + ((size_t)which * 1024 + head * 64) * 1024;
#pragma unroll
  for (int i = 0; i < 4; ++i) {
    int r = i * 16 + (tid >> 4);  // c within tile
    int c = (tid & 15) * 4;       // d
    float4 v = *(const float4*)&src[(size_t)(k0 + r) * 64 + c];
    t[c + 0][r] = (bf16)(v.x * scale);
    t[c + 1][r] = (bf16)(v.y * scale);
    t[c + 2][r] = (bf16)(v.z * scale);
    t[c + 3][r] = (bf16)(v.w * scale);
  }
  __syncthreads();
#pragma unroll
  for (int i = 0; i < 2; ++i) {
    int r = i * 32 + (tid >> 3);  // d row
    int c = (tid & 7) * 8;        // c col
    bf16x8 o;
#pragma unroll
    for (int j = 0; j < 8; ++j) o[j] = t[r][c + j];
    *(bf16x8*)&dst[(size_t)r * 1024 + k0 + c] = o;
  }
}

// W [K,N] fp32 -> WT [N,K] bf16, tiled 64x64
__global__ __launch_bounds__(256) void transpose_conv(
    const float* __restrict__ W, bf16* __restrict__ WT, int K, int N) {
  __shared__ bf16 t[64][72];
  int tid = threadIdx.x;
  int n0 = blockIdx.x * 64, k0 = blockIdx.y * 64;
#pragma unroll
  for (int i = 0; i < 4; ++i) {
    int r = i * 16 + (tid >> 4);  // k
    int c = (tid & 15) * 4;       // n
    float4 v = *(const float4*)&W[(size_t)(k0 + r) * N + n0 + c];
    t[c + 0][r] = (bf16)v.x;
    t[c + 1][r] = (bf16)v.y;
    t[c + 2][r] = (bf16)v.z;
    t[c + 3][r] = (bf16)v.w;
  }
  __syncthreads();
#pragma unroll
  for (int i = 0; i < 2; ++i) {
    int r = i * 32 + (tid >> 3);  // n
    int c = (tid & 7) * 8;        // k
    bf16x8 o;
#pragma unroll
    for (int j = 0; j < 8; ++j) o[j] = t[r][c + j];
    *(bf16x8*)&WT[(size_t)(n0 + r) * K + k0 + c] = o;
  }
}

// v [B,H,T,Dh] bf16 -> vt [B,H,Dh,T] bf16, per-bh 64x64 tiles
__global__ __launch_bounds__(256) void transpose_v(const bf16* __restrict__ v,
                                                   bf16* __restrict__ vt) {
  __shared__ bf16 t[64][72];
  int bh = blockIdx.y;
  int t0 = blockIdx.x * 64;
  const bf16* src = v + (size_t)bh * 131072;
  bf16* dst = vt + (size_t)bh * 131072;
  int tid = threadIdx.x;
#pragma unroll
  for (int i = 0; i < 2; ++i) {
    int c = tid + i * 256;
    int r = c >> 3, d0 = (c & 7) * 8;
    bf16x8 vv = *(const bf16x8*)&src[(size_t)(t0 + r) * 64 + d0];
#pragma unroll
    for (int j = 0; j < 8; ++j) t[d0 + j][r] = vv[j];
  }
  __syncthreads();
#pragma unroll
  for (int i = 0; i < 2; ++i) {
    int c = tid + i * 256;
    int r = c >> 3, s0 = (c & 7) * 8;
    bf16x8 o;
#pragma unroll
    for (int j = 0; j < 8; ++j) o[j] = t[r][s0 + j];
    *(bf16x8*)&dst[(size_t)r * 2048 + t0 + s0] = o;
  }
}

// ---------------- layernorm (fp32 in -> bf16 out) ----------------
__global__ __launch_bounds__(256) void ln_kernel(
    const float* __restrict__ x, const float* __restrict__ g,
    const float* __restrict__ bta, bf16* __restrict__ out) {
  int row = blockIdx.x;
  const float* xr = x + (size_t)row * EMBED;
  float4 v = ((const float4*)xr)[threadIdx.x];
  float s1 = v.x + v.y + v.z + v.w;
  float s2 = v.x * v.x + v.y * v.y + v.z * v.z + v.w * v.w;
#pragma unroll
  for (int off = 1; off < 64; off <<= 1) {
    s1 += __shfl_xor(s1, off);
    s2 += __shfl_xor(s2, off);
  }
  __shared__ float red[8];
  int wid = threadIdx.x >> 6;
  int lane = threadIdx.x & 63;
  if (lane == 0) {
    red[wid * 2] = s1;
    red[wid * 2 + 1] = s2;
  }
  __syncthreads();
  s1 = red[0] + red[2] + red[4] + red[6];
  s2 = red[1] + red[3] + red[5] + red[7];
  float mu = s1 * (1.0f / EMBED);
  float var = s2 * (1.0f / EMBED) - mu * mu;
  float rs = rsqrtf(var + 1e-5f);
  float4 gv = ((const float4*)g)[threadIdx.x];
  float4 bv = ((const float4*)bta)[threadIdx.x];
  bf16x4 o;
  o[0] = (bf16)((v.x - mu) * rs * gv.x + bv.x);
  o[1] = (bf16)((v.y - mu) * rs * gv.y + bv.y);
  o[2] = (bf16)((v.z - mu) * rs * gv.z + bv.z);
  o[3] = (bf16)((v.w - mu) * rs * gv.w + bv.w);
  *(bf16x4*)(out + (size_t)row * EMBED + threadIdx.x * 4) = o;
}

// ---------------- 256x256 GEMM, BK=32, 3 LDS buffers, 2-phase interleave ----------------
template <int EPI>
__global__ __launch_bounds__(512, 1) void gemm256(
    const bf16* __restrict__ A, const bf16* __restrict__ BT,
    bf16* __restrict__ Cb, const float* __restrict__ bias, int M, int N,
    int K) {
  __shared__ __attribute__((aligned(16))) char lds[98304];  // 3 x (A16K + B16K)
  int gx = gridDim.x;
  int nwg = gx * gridDim.y;
  int wgid = blockIdx.y * gx + blockIdx.x;
  int cpx = nwg >> 3;
  int swz = (wgid & 7) * cpx + (wgid >> 3);
  int m0 = (swz / gx) * 256, n0 = (swz % gx) * 256;
  int tid = threadIdx.x;
  int lane = tid & 63, wid = tid >> 6;
  int lr = lane & 15, lg = lane >> 4;
  int wrM = (wid >> 2) * 128;  // wave M base: 0 or 128
  int wcN = (wid & 3) * 64;    // wave N base: 0/64/128/192
  int crow = lane >> 2;        // staging row within 16-row chunk
  int slotg = (lane & 3) ^ (crow & 3);  // inverse-swizzled global 16B slot
  int NT = K >> 5;
  size_t rb = (size_t)K * 2;  // bytes per row of A / BT

  auto stageA = [&](int t) {
    char* dst = lds + ((unsigned)t % 3u) * 32768u;
#pragma unroll
    for (int q = 0; q < 2; ++q) {
      int c = wid * 2 + q;  // chunk 0..15 (16 rows each)
      const char* srcA = (const char*)A + (size_t)(m0 + c * 16 + crow) * rb +
                         (size_t)t * 64 + slotg * 16;
      __builtin_amdgcn_global_load_lds((gvp)srcA, (svp)(dst + c * 1024), 16, 0,
                                       0);
    }
  };
  auto stageB = [&](int t) {
    char* dst = lds + ((unsigned)t % 3u) * 32768u + 16384u;
#pragma unroll
    for (int q = 0; q < 2; ++q) {
      int c = wid * 2 + q;
      const char* srcB = (const char*)BT + (size_t)(n0 + c * 16 + crow) * rb +
                         (size_t)t * 64 + slotg * 16;
      __builtin_amdgcn_global_load_lds((gvp)srcB, (svp)(dst + c * 1024), 16, 0,
                                       0);
    }
  };

  stageA(0);
  stageB(0);
  stageA(1);
  stageB(1);
  f32x4 acc[8][4] = {};
  int swcol = ((lg ^ (lr & 3)) * 16);
  for (int t = 0; t < NT; ++t) {
    if (t == NT - 1)
      asm volatile("s_waitcnt vmcnt(0)" ::: "memory");
    else
      asm volatile("s_waitcnt vmcnt(4)" ::: "memory");
    __builtin_amdgcn_s_barrier();
    __builtin_amdgcn_sched_barrier(0);
    const char* Ab = lds + ((unsigned)t % 3u) * 32768u;
    const char* Bb = Ab + 16384;
    int tn = t + 2;
    bool st = tn < NT;
    // ---- phase A ----
    bf16x8 bfr[4], afA[4], afB[4];
#pragma unroll
    for (int j = 0; j < 4; ++j)
      bfr[j] = *(const bf16x8*)(Bb + (wcN + j * 16 + lr) * 64 + swcol);
#pragma unroll
    for (int i = 0; i < 4; ++i)
      afA[i] = *(const bf16x8*)(Ab + (wrM + i * 16 + lr) * 64 + swcol);
    if (st) stageA(tn);
    __builtin_amdgcn_s_barrier();
    __builtin_amdgcn_sched_barrier(0);
    __builtin_amdgcn_s_setprio(1);
#pragma unroll
    for (int i = 0; i < 4; ++i)
#pragma unroll
      for (int j = 0; j < 4; ++j)
        acc[i][j] = __builtin_amdgcn_mfma_f32_16x16x32_bf16(afA[i], bfr[j],
                                                            acc[i][j], 0, 0, 0);
    __builtin_amdgcn_s_setprio(0);
    __builtin_amdgcn_sched_barrier(0);
    // ---- phase B ----
#pragma unroll
    for (int i = 0; i < 4; ++i)
      afB[i] = *(const bf16x8*)(Ab + (wrM + 64 + i * 16 + lr) * 64 + swcol);
    if (st) stageB(tn);
    __builtin_amdgcn_s_barrier();
    __builtin_amdgcn_sched_barrier(0);
    __builtin_amdgcn_s_setprio(1);
#pragma unroll
    for (int i = 0; i < 4; ++i)
#pragma unroll
      for (int j = 0; j < 4; ++j)
        acc[4 + i][j] = __builtin_amdgcn_mfma_f32_16x16x32_bf16(
            afB[i], bfr[j], acc[4 + i][j], 0, 0, 0);
    __builtin_amdgcn_s_setprio(0);
    __builtin_amdgcn_sched_barrier(0);
  }
#pragma unroll
  for (int i = 0; i < 8; ++i) {
#pragma unroll
    for (int j = 0; j < 4; ++j) {
#pragma unroll
      for (int r = 0; r < 4; ++r) {
        int row = m0 + wrM + i * 16 + lg * 4 + r;
        int col = n0 + wcN + j * 16 + lr;
        float v = acc[i][j][r];
        if (EPI == 0) {
          int which = col >> 10, cc = col & 1023;
          int b = row >> 11, tt = row & 2047, h = cc >> 6, d = cc & 63;
          bf16* dst = Cb + (size_t)which * 8388608;
          dst[((size_t)((b << 4) + h) * TSEQ + tt) * HEAD_DIM + d] = (bf16)v;
        } else {
          size_t o = (size_t)row * N + col;
          float u = v + bias[col];
          Cb[o] = (bf16)(u > 0.f ? u : 0.f);
        }
      }
    }
  }
}

// ---------------- 256x128 GEMM + residual epilogue (fp32 out), 2-phase pipeline ----------
// C[M,N] = resid + bias + A[M,K]*BT[N,K]^T. 512 threads = 8 waves (4M x 2N),
// wave tile 64x64. 3 LDS buffers x (A 16KB + B 8KB) = 72KB -> 2 blocks/CU.
// 3 gload_lds per wave per tile (2 A + 1 B) -> vmcnt(3) counted wait.
__global__ __launch_bounds__(512, 2) void gemm_res(
    const bf16* __restrict__ A, const bf16* __restrict__ BT,
    float* __restrict__ Cf, const float* __restrict__ bias,
    const float* __restrict__ resid, int M, int N, int K) {
  __shared__ __attribute__((aligned(16))) char lds[73728];  // 3 x 24KB
  int gx = gridDim.x;
  int nwg = gx * gridDim.y;
  int wgid = blockIdx.y * gx + blockIdx.x;
  int cpx = nwg >> 3;
  int swz = (wgid & 7) * cpx + (wgid >> 3);
  int m0 = (swz / gx) * 256, n0 = (swz % gx) * 128;
  int tid = threadIdx.x;
  int lane = tid & 63, wid = tid >> 6;
  int lr = lane & 15, lg = lane >> 4;
  int wrM = (wid >> 1) * 64;  // wave M base: 0/64/128/192
  int wcN = (wid & 1) * 64;   // wave N base: 0/64
  int crow = lane >> 2;
  int slotg = (lane & 3) ^ (crow & 3);
  int NT = K >> 5;
  size_t rb = (size_t)K * 2;

  auto stageA = [&](int t) {
    char* dst = lds + ((unsigned)t % 3u) * 24576u;
#pragma unroll
    for (int q = 0; q < 2; ++q) {
      int c = wid * 2 + q;  // chunk 0..15 (16 rows each)
      const char* srcA = (const char*)A + (size_t)(m0 + c * 16 + crow) * rb +
                         (size_t)t * 64 + slotg * 16;
      __builtin_amdgcn_global_load_lds((gvp)srcA, (svp)(dst + c * 1024), 16, 0,
                                       0);
    }
  };
  auto stageB = [&](int t) {
    char* dst = lds + ((unsigned)t % 3u) * 24576u + 16384u;
    const char* srcB = (const char*)BT + (size_t)(n0 + wid * 16 + crow) * rb +
                       (size_t)t * 64 + slotg * 16;
    __builtin_amdgcn_global_load_lds((gvp)srcB, (svp)(dst + wid * 1024), 16, 0,
                                     0);
  };

  stageA(0);
  stageB(0);
  stageA(1);
  stageB(1);
  f32x4 acc[4][4] = {};
  int swcol = ((lg ^ (lr & 3)) * 16);
  for (int t = 0; t < NT; ++t) {
    if (t == NT - 1)
      asm volatile("s_waitcnt vmcnt(0)" ::: "memory");
    else
      asm volatile("s_waitcnt vmcnt(3)" ::: "memory");
    __builtin_amdgcn_s_barrier();
    __builtin_amdgcn_sched_barrier(0);
    const char* Ab = lds + ((unsigned)t % 3u) * 24576u;
    const char* Bb = Ab + 16384;
    int tn = t + 2;
    bool st = tn < NT;
    // ---- phase A ----
    bf16x8 bfr[4], afA[2], afB[2];
#pragma unroll
    for (int j = 0; j < 4; ++j)
      bfr[j] = *(const bf16x8*)(Bb + (wcN + j * 16 + lr) * 64 + swcol);
#pragma unroll
    for (int i = 0; i < 2; ++i)
      afA[i] = *(const bf16x8*)(Ab + (wrM + i * 16 + lr) * 64 + swcol);
    if (st) stageA(tn);
    __builtin_amdgcn_s_barrier();
    __builtin_amdgcn_sched_barrier(0);
    __builtin_amdgcn_s_setprio(1);
#pragma unroll
    for (int i = 0; i < 2; ++i)
#pragma unroll
      for (int j = 0; j < 4; ++j)
        acc[i][j] = __builtin_amdgcn_mfma_f32_16x16x32_bf16(afA[i], bfr[j],
                                                            acc[i][j], 0, 0, 0);
    __builtin_amdgcn_s_setprio(0);
    __builtin_amdgcn_sched_barrier(0);
    // ---- phase B ----
#pragma unroll
    for (int i = 0; i < 2; ++i)
      afB[i] = *(const bf16x8*)(Ab + (wrM + 32 + i * 16 + lr) * 64 + swcol);
    if (st) stageB(tn);
    __builtin_amdgcn_s_barrier();
    __builtin_amdgcn_sched_barrier(0);
    __builtin_amdgcn_s_setprio(1);
#pragma unroll
    for (int i = 0; i < 2; ++i)
#pragma unroll
      for (int j = 0; j < 4; ++j)
        acc[2 + i][j] = __builtin_amdgcn_mfma_f32_16x16x32_bf16(
            afB[i], bfr[j], acc[2 + i][j], 0, 0, 0);
    __builtin_amdgcn_s_setprio(0);
    __builtin_amdgcn_sched_barrier(0);
  }
#pragma unroll
  for (int i = 0; i < 4; ++i) {
#pragma unroll
    for (int j = 0; j < 4; ++j) {
#pragma unroll
      for (int r = 0; r < 4; ++r) {
        int row = m0 + wrM + i * 16 + lg * 4 + r;
        int col = n0 + wcN + j * 16 + lr;
        size_t o = (size_t)row * N + col;
        Cf[o] = resid[o] + bias[col] + acc[i][j][r];
      }
    }
  }
}

// ---------------- causal flash attention: QBLK=128, rg=2, fixed-shift softmax,
// deferred row-sum, 32KB XOR-swizzled LDS (5 blocks/CU) ----------------------------
// grid (64, 16) x 256: x = bh (XCD L2 locality), y -> Q = 15-y (longest first)
__global__ __launch_bounds__(256) void attn_kernel(
    const bf16* __restrict__ q, const bf16* __restrict__ k,
    const bf16* __restrict__ vt, bf16* __restrict__ out) {
  // Ks 8KB | Vs 8KB | Ps 16KB (4KB/wave), all XOR-swizzled: byte ^= (row&7)<<4
  __shared__ __attribute__((aligned(16))) char ldsK[8192];
  __shared__ __attribute__((aligned(16))) char ldsV[8192];
  __shared__ __attribute__((aligned(16))) char ldsP[16384];
  int bh = blockIdx.x;
  int b = bh >> 4, h = bh & 15;
  const bf16* qb = q + (size_t)bh * TSEQ * HEAD_DIM;
  const bf16* kb = k + (size_t)bh * TSEQ * HEAD_DIM;
  const bf16* vb = vt + (size_t)bh * HEAD_DIM * TSEQ;
  int tid = threadIdx.x, lane = tid & 63, w = tid >> 6;
  int lr = lane & 15, lg = lane >> 4;
  int Q = 15 - blockIdx.y;     // supertile of 128 rows; longest job first
  int tw = Q * 128 + w * 32;   // wave's base row
  int srow0 = tid >> 3;        // staging rows 0..31 (i=0), +32 (i=1)
  int scol = (tid & 7) * 16;   // byte col
  bf16x8 aq[2][2];
#pragma unroll
  for (int rg = 0; rg < 2; ++rg)
#pragma unroll
    for (int kc = 0; kc < 2; ++kc)
      aq[rg][kc] = *(const bf16x8*)&qb[(size_t)(tw + rg * 16 + lr) * HEAD_DIM +
                                       kc * 32 + lg * 8];
  f32x4 o[2][4] = {};
  float sacc[2][4] = {};
  char* myP = ldsP + w * 4096;
  int nj = 2 * Q + 2;
  for (int j = 0; j < nj; ++j) {
#pragma unroll
    for (int i = 0; i < 2; ++i) {
      int rr = srow0 + i * 32;
      int sw = scol ^ ((rr & 7) << 4);
      *(bf16x8*)(ldsK + rr * 128 + sw) =
          *(const bf16x8*)&kb[(size_t)(j * 64 + rr) * HEAD_DIM + (scol >> 1)];
      *(bf16x8*)(ldsV + rr * 128 + sw) =
          *(const bf16x8*)&vb[(size_t)rr * TSEQ + j * 64 + (scol >> 1)];
    }
    __syncthreads();
    f32x4 s[2][4] = {};
#pragma unroll
    for (int nb = 0; nb < 4; ++nb) {
      int rowK = nb * 16 + lr;
#pragma unroll
      for (int kc = 0; kc < 2; ++kc) {
        int cb = (kc * 64 + lg * 16) ^ ((rowK & 7) << 4);
        bf16x8 bk = *(const bf16x8*)(ldsK + rowK * 128 + cb);
        s[0][nb] = __builtin_amdgcn_mfma_f32_16x16x32_bf16(aq[0][kc], bk,
                                                           s[0][nb], 0, 0, 0);
        s[1][nb] = __builtin_amdgcn_mfma_f32_16x16x32_bf16(aq[1][kc], bk,
                                                           s[1][nb], 0, 0, 0);
      }
    }
    if (j >= 2 * Q) {  // boundary tiles: causal mask
#pragma unroll
      for (int rg = 0; rg < 2; ++rg)
#pragma unroll
        for (int nb = 0; nb < 4; ++nb)
#pragma unroll
          for (int r = 0; r < 4; ++r) {
            int sg = j * 64 + nb * 16 + lr;
            int tg = tw + rg * 16 + lg * 4 + r;
            if (sg > tg) s[rg][nb][r] = -1e30f;
          }
    }
#pragma unroll
    for (int rg = 0; rg < 2; ++rg) {
#pragma unroll
      for (int r = 0; r < 4; ++r) {
        int rowP = rg * 16 + lg * 4 + r;
        int swr = (rowP & 7) << 4;
        float psum = 0.f;
#pragma unroll
        for (int nb = 0; nb < 4; ++nb) {
          float p = exp2f(s[rg][nb][r] - 8.0f);
          psum += p;
          *(bf16*)(myP + rowP * 128 + (((nb * 16 + lr) * 2) ^ swr)) = (bf16)p;
        }
        sacc[rg][r] += psum;  // deferred: no per-j shuffle reduce
      }
    }
    // P is per-wave: no barrier needed between store and read
#pragma unroll
    for (int kc = 0; kc < 2; ++kc) {
      int cb0 = (kc * 64 + lg * 16) ^ ((lr & 7) << 4);
      bf16x8 pa0 = *(const bf16x8*)(myP + lr * 128 + cb0);
      bf16x8 pa1 = *(const bf16x8*)(myP + (16 + lr) * 128 + cb0);
#pragma unroll
      for (int br = 0; br < 4; ++br) {
        int rowV = br * 16 + lr;
        int cbv = (kc * 64 + lg * 16) ^ ((rowV & 7) << 4);
        bf16x8 bv = *(const bf16x8*)(ldsV + rowV * 128 + cbv);
        o[0][br] =
            __builtin_amdgcn_mfma_f32_16x16x32_bf16(pa0, bv, o[0][br], 0, 0, 0);
        o[1][br] =
            __builtin_amdgcn_mfma_f32_16x16x32_bf16(pa1, bv, o[1][br], 0, 0, 0);
      }
    }
    __syncthreads();
  }
  float lrow[2][4];
#pragma unroll
  for (int rg = 0; rg < 2; ++rg)
#pragma unroll
    for (int r = 0; r < 4; ++r) {
      float su = sacc[rg][r];
#pragma unroll
      for (int off = 1; off < 16; off <<= 1) su += __shfl_xor(su, off);
      lrow[rg][r] = su;
    }
#pragma unroll
  for (int rg = 0; rg < 2; ++rg)
#pragma unroll
    for (int br = 0; br < 4; ++br)
#pragma unroll
      for (int r = 0; r < 4; ++r) {
        int t = tw + rg * 16 + lg * 4 + r;
        int d = br * 16 + lr;
        float val = o[rg][br][r] / lrow[rg][r];
        out[((size_t)(b * TSEQ) + t) * EMBED + h * HEAD_DIM + d] = (bf16)val;
      }
}

// ---------------- launch ----------------
extern "C" void kernel_launch(void* const* d_in, const int* in_sizes, int n_in,
                              void* d_out, int out_size, void* d_ws,
                              size_t ws_size, hipStream_t stream) {
  const float* x = (const float*)d_in[0];
  const float* Wq = (const float*)d_in[1];
  const float* Wk = (const float*)d_in[2];
  const float* Wv = (const float*)d_in[3];
  const float* Wo = (const float*)d_in[4];
  const float* bo = (const float*)d_in[5];
  const float* W1 = (const float*)d_in[6];
  const float* b1 = (const float*)d_in[7];
  const float* W2 = (const float*)d_in[8];
  const float* b2 = (const float*)d_in[9];
  const float* g1 = (const float*)d_in[10];
  const float* be1 = (const float*)d_in[11];
  const float* g2 = (const float*)d_in[12];
  const float* be2 = (const float*)d_in[13];
  float* out = (float*)d_out;
  char* ws = (char*)d_ws;

  const size_t U = 16777216;  // 16 MiB
  bf16* h = (bf16*)(ws + 0 * U);
  bf16* qb = (bf16*)(ws + 1 * U);
  bf16* vtb = (bf16*)(ws + 0 * U);
  bf16* vnb = (bf16*)(ws + 3 * U);
  bf16* ao = (bf16*)(ws + 3 * U);
  float* x1 = (float*)(ws + 4 * U);
  bf16* h2 = (bf16*)(ws + 6 * U);
  bf16* ff1 = (bf16*)(ws + 0 * U);
  char* wbase = ws + 7 * U;
  bf16* WqkvT = (bf16*)(wbase);           // 6 MB
  bf16* WoT = (bf16*)(wbase + 6291456);   // 2 MB
  bf16* W1T = (bf16*)(wbase + 8388608);   // 8 MB
  bf16* W2T = (bf16*)(wbase + 16777216);  // 8 MB

  hipLaunchKernelGGL(conv_wqkv_t, dim3(16, 16, 3), dim3(256), 0, stream, Wq,
                     Wk, Wv, WqkvT);
  hipLaunchKernelGGL(transpose_conv, dim3(16, 16), dim3(256), 0, stream, Wo,
                     WoT, 1024, 1024);
  hipLaunchKernelGGL(transpose_conv, dim3(64, 16), dim3(256), 0, stream, W1,
                     W1T, 1024, 4096);
  hipLaunchKernelGGL(transpose_conv, dim3(16, 64), dim3(256), 0, stream, W2,
                     W2T, 4096, 1024);
  hipLaunchKernelGGL(ln_kernel, dim3(8192), dim3(256), 0, stream, x, g1, be1,
                     h);
  // fused QKV projection: 256x256 2-phase pipelined GEMM, scatter epilogue
  hipLaunchKernelGGL((gemm256<0>), dim3(12, 32), dim3(512), 0, stream, h,
                     WqkvT, qb, (const float*)nullptr, ROWS, 3072, 1024);
  // v [B,H,T,D] -> vt [B,H,D,T]
  hipLaunchKernelGGL(transpose_v, dim3(32, 64), dim3(256), 0, stream, vnb,
                     vtb);
  // attention (QBLK=128, rg=2, fixed-shift softmax, deferred sum, 32KB LDS)
  hipLaunchKernelGGL(attn_kernel, dim3(64, 16), dim3(256), 0, stream, qb,
                     qb + 8388608, vtb, ao);
  // x1 = x + ao @ Wo + bo : 256x128 pipelined GEMM with residual epilogue
  hipLaunchKernelGGL(gemm_res, dim3(8, 32), dim3(512), 0, stream, ao, WoT, x1,
                     bo, x, ROWS, 1024, 1024);
  // h2 = LN2(x1)
  hipLaunchKernelGGL(ln_kernel, dim3(8192), dim3(256), 0, stream, x1, g2, be2,
                     h2);
  // ff1 = relu(h2 @ W1 + b1): 256x256 2-phase pipelined GEMM
  hipLaunchKernelGGL((gemm256<3>), dim3(16, 32), dim3(512), 0, stream, h2, W1T,
                     ff1, b1, ROWS, 4096, 1024);
  // out = x1 + ff1 @ W2 + b2 : 256x128 pipelined GEMM with residual epilogue
  hipLaunchKernelGGL(gemm_res, dim3(8, 32), dim3(512), 0, stream, ff1, W2T,
                     out, b2, x1, ROWS, 1024, 4096);
}

// Round 12
// 398.778 us; speedup vs baseline: 1.2288x; 1.0097x over previous
//
#include <hip/hip_runtime.h>
#include <hip/hip_bf16.h>

#define EMBED 1024
#define HEADS 16
#define HEAD_DIM 64
#define FFDIM 4096
#define TSEQ 2048
#define BATCH 4
#define ROWS (BATCH * TSEQ)  // 8192

typedef __bf16 bf16;
typedef __attribute__((ext_vector_type(8))) __bf16 bf16x8;
typedef __attribute__((ext_vector_type(4))) __bf16 bf16x4;
typedef __attribute__((ext_vector_type(4))) float f32x4;
typedef __attribute__((ext_vector_type(16))) float f32x16;

typedef const __attribute__((address_space(1))) void* gvp;
typedef __attribute__((address_space(3))) void* svp;

__device__ inline unsigned pk2(float a, float b) {
  union { bf16 h[2]; unsigned u; } x;
  x.h[0] = (bf16)a;
  x.h[1] = (bf16)b;
  return x.u;
}

// ---------------- weight conversion (LDS-tiled transposes, coalesced) ----------------
__global__ __launch_bounds__(256) void conv_wqkv_t(
    const float* __restrict__ Wq, const float* __restrict__ Wk,
    const float* __restrict__ Wv, bf16* __restrict__ WqkvT) {
  __shared__ bf16 t[64][72];
  int tid = threadIdx.x;
  int k0 = blockIdx.x * 64;  // c-tile
  int head = blockIdx.y;
  int which = blockIdx.z;
  const float* src = which == 0 ? Wq : which == 1 ? Wk : Wv;
  float scale = which == 0 ? 0.125f * 1.44269504088896f : 1.0f;
  src += (size_t)head * 65536;
  bf16* dst = WqkvT + ((size_t)which * 1024 + head * 64) * 1024;
#pragma unroll
  for (int i = 0; i < 4; ++i) {
    int r = i * 16 + (tid >> 4);  // c within tile
    int c = (tid & 15) * 4;       // d
    float4 v = *(const float4*)&src[(size_t)(k0 + r) * 64 + c];
    t[c + 0][r] = (bf16)(v.x * scale);
    t[c + 1][r] = (bf16)(v.y * scale);
    t[c + 2][r] = (bf16)(v.z * scale);
    t[c + 3][r] = (bf16)(v.w * scale);
  }
  __syncthreads();
#pragma unroll
  for (int i = 0; i < 2; ++i) {
    int r = i * 32 + (tid >> 3);  // d row
    int c = (tid & 7) * 8;        // c col
    bf16x8 o;
#pragma unroll
    for (int j = 0; j < 8; ++j) o[j] = t[r][c + j];
    *(bf16x8*)&dst[(size_t)r * 1024 + k0 + c] = o;
  }
}

// W [K,N] fp32 -> WT [N,K] bf16, tiled 64x64
__global__ __launch_bounds__(256) void transpose_conv(
    const float* __restrict__ W, bf16* __restrict__ WT, int K, int N) {
  __shared__ bf16 t[64][72];
  int tid = threadIdx.x;
  int n0 = blockIdx.x * 64, k0 = blockIdx.y * 64;
#pragma unroll
  for (int i = 0; i < 4; ++i) {
    int r = i * 16 + (tid >> 4);  // k
    int c = (tid & 15) * 4;       // n
    float4 v = *(const float4*)&W[(size_t)(k0 + r) * N + n0 + c];
    t[c + 0][r] = (bf16)v.x;
    t[c + 1][r] = (bf16)v.y;
    t[c + 2][r] = (bf16)v.z;
    t[c + 3][r] = (bf16)v.w;
  }
  __syncthreads();
#pragma unroll
  for (int i = 0; i < 2; ++i) {
    int r = i * 32 + (tid >> 3);  // n
    int c = (tid & 7) * 8;        // k
    bf16x8 o;
#pragma unroll
    for (int j = 0; j < 8; ++j) o[j] = t[r][c + j];
    *(bf16x8*)&WT[(size_t)(n0 + r) * K + k0 + c] = o;
  }
}

// v [B,H,T,Dh] bf16 -> vt [B,H,Dh,T] bf16, per-bh 64x64 tiles
__global__ __launch_bounds__(256) void transpose_v(const bf16* __restrict__ v,
                                                   bf16* __restrict__ vt) {
  __shared__ bf16 t[64][72];
  int bh = blockIdx.y;
  int t0 = blockIdx.x * 64;
  const bf16* src = v + (size_t)bh * 131072;
  bf16* dst = vt + (size_t)bh * 131072;
  int tid = threadIdx.x;
#pragma unroll
  for (int i = 0; i < 2; ++i) {
    int c = tid + i * 256;
    int r = c >> 3, d0 = (c & 7) * 8;
    bf16x8 vv = *(const bf16x8*)&src[(size_t)(t0 + r) * 64 + d0];
#pragma unroll
    for (int j = 0; j < 8; ++j) t[d0 + j][r] = vv[j];
  }
  __syncthreads();
#pragma unroll
  for (int i = 0; i < 2; ++i) {
    int c = tid + i * 256;
    int r = c >> 3, s0 = (c & 7) * 8;
    bf16x8 o;
#pragma unroll
    for (int j = 0; j < 8; ++j) o[j] = t[r][s0 + j];
    *(bf16x8*)&dst[(size_t)r * 2048 + t0 + s0] = o;
  }
}

// ---------------- layernorm (fp32 in -> bf16 out) ----------------
__global__ __launch_bounds__(256) void ln_kernel(
    const float* __restrict__ x, const float* __restrict__ g,
    const float* __restrict__ bta, bf16* __restrict__ out) {
  int row = blockIdx.x;
  const float* xr = x + (size_t)row * EMBED;
  float4 v = ((const float4*)xr)[threadIdx.x];
  float s1 = v.x + v.y + v.z + v.w;
  float s2 = v.x * v.x + v.y * v.y + v.z * v.z + v.w * v.w;
#pragma unroll
  for (int off = 1; off < 64; off <<= 1) {
    s1 += __shfl_xor(s1, off);
    s2 += __shfl_xor(s2, off);
  }
  __shared__ float red[8];
  int wid = threadIdx.x >> 6;
  int lane = threadIdx.x & 63;
  if (lane == 0) {
    red[wid * 2] = s1;
    red[wid * 2 + 1] = s2;
  }
  __syncthreads();
  s1 = red[0] + red[2] + red[4] + red[6];
  s2 = red[1] + red[3] + red[5] + red[7];
  float mu = s1 * (1.0f / EMBED);
  float var = s2 * (1.0f / EMBED) - mu * mu;
  float rs = rsqrtf(var + 1e-5f);
  float4 gv = ((const float4*)g)[threadIdx.x];
  float4 bv = ((const float4*)bta)[threadIdx.x];
  bf16x4 o;
  o[0] = (bf16)((v.x - mu) * rs * gv.x + bv.x);
  o[1] = (bf16)((v.y - mu) * rs * gv.y + bv.y);
  o[2] = (bf16)((v.z - mu) * rs * gv.z + bv.z);
  o[3] = (bf16)((v.w - mu) * rs * gv.w + bv.w);
  *(bf16x4*)(out + (size_t)row * EMBED + threadIdx.x * 4) = o;
}

// ---------------- 256x256 GEMM, BK=32, 3 LDS buffers, 2-phase interleave ----------------
template <int EPI>
__global__ __launch_bounds__(512, 1) void gemm256(
    const bf16* __restrict__ A, const bf16* __restrict__ BT,
    bf16* __restrict__ Cb, const float* __restrict__ bias, int M, int N,
    int K) {
  __shared__ __attribute__((aligned(16))) char lds[98304];  // 3 x (A16K + B16K)
  int gx = gridDim.x;
  int nwg = gx * gridDim.y;
  int wgid = blockIdx.y * gx + blockIdx.x;
  int cpx = nwg >> 3;
  int swz = (wgid & 7) * cpx + (wgid >> 3);
  int m0 = (swz / gx) * 256, n0 = (swz % gx) * 256;
  int tid = threadIdx.x;
  int lane = tid & 63, wid = tid >> 6;
  int lr = lane & 15, lg = lane >> 4;
  int wrM = (wid >> 2) * 128;  // wave M base: 0 or 128
  int wcN = (wid & 3) * 64;    // wave N base: 0/64/128/192
  int crow = lane >> 2;        // staging row within 16-row chunk
  int slotg = (lane & 3) ^ (crow & 3);  // inverse-swizzled global 16B slot
  int NT = K >> 5;
  size_t rb = (size_t)K * 2;  // bytes per row of A / BT

  auto stageA = [&](int t) {
    char* dst = lds + ((unsigned)t % 3u) * 32768u;
#pragma unroll
    for (int q = 0; q < 2; ++q) {
      int c = wid * 2 + q;  // chunk 0..15 (16 rows each)
      const char* srcA = (const char*)A + (size_t)(m0 + c * 16 + crow) * rb +
                         (size_t)t * 64 + slotg * 16;
      __builtin_amdgcn_global_load_lds((gvp)srcA, (svp)(dst + c * 1024), 16, 0,
                                       0);
    }
  };
  auto stageB = [&](int t) {
    char* dst = lds + ((unsigned)t % 3u) * 32768u + 16384u;
#pragma unroll
    for (int q = 0; q < 2; ++q) {
      int c = wid * 2 + q;
      const char* srcB = (const char*)BT + (size_t)(n0 + c * 16 + crow) * rb +
                         (size_t)t * 64 + slotg * 16;
      __builtin_amdgcn_global_load_lds((gvp)srcB, (svp)(dst + c * 1024), 16, 0,
                                       0);
    }
  };

  stageA(0);
  stageB(0);
  stageA(1);
  stageB(1);
  f32x4 acc[8][4] = {};
  int swcol = ((lg ^ (lr & 3)) * 16);
  for (int t = 0; t < NT; ++t) {
    if (t == NT - 1)
      asm volatile("s_waitcnt vmcnt(0)" ::: "memory");
    else
      asm volatile("s_waitcnt vmcnt(4)" ::: "memory");
    __builtin_amdgcn_s_barrier();
    __builtin_amdgcn_sched_barrier(0);
    const char* Ab = lds + ((unsigned)t % 3u) * 32768u;
    const char* Bb = Ab + 16384;
    int tn = t + 2;
    bool st = tn < NT;
    // ---- phase A ----
    bf16x8 bfr[4], afA[4], afB[4];
#pragma unroll
    for (int j = 0; j < 4; ++j)
      bfr[j] = *(const bf16x8*)(Bb + (wcN + j * 16 + lr) * 64 + swcol);
#pragma unroll
    for (int i = 0; i < 4; ++i)
      afA[i] = *(const bf16x8*)(Ab + (wrM + i * 16 + lr) * 64 + swcol);
    if (st) stageA(tn);
    __builtin_amdgcn_s_barrier();
    __builtin_amdgcn_sched_barrier(0);
    __builtin_amdgcn_s_setprio(1);
#pragma unroll
    for (int i = 0; i < 4; ++i)
#pragma unroll
      for (int j = 0; j < 4; ++j)
        acc[i][j] = __builtin_amdgcn_mfma_f32_16x16x32_bf16(afA[i], bfr[j],
                                                            acc[i][j], 0, 0, 0);
    __builtin_amdgcn_s_setprio(0);
    __builtin_amdgcn_sched_barrier(0);
    // ---- phase B ----
#pragma unroll
    for (int i = 0; i < 4; ++i)
      afB[i] = *(const bf16x8*)(Ab + (wrM + 64 + i * 16 + lr) * 64 + swcol);
    if (st) stageB(tn);
    __builtin_amdgcn_s_barrier();
    __builtin_amdgcn_sched_barrier(0);
    __builtin_amdgcn_s_setprio(1);
#pragma unroll
    for (int i = 0; i < 4; ++i)
#pragma unroll
      for (int j = 0; j < 4; ++j)
        acc[4 + i][j] = __builtin_amdgcn_mfma_f32_16x16x32_bf16(
            afB[i], bfr[j], acc[4 + i][j], 0, 0, 0);
    __builtin_amdgcn_s_setprio(0);
    __builtin_amdgcn_sched_barrier(0);
  }
#pragma unroll
  for (int i = 0; i < 8; ++i) {
#pragma unroll
    for (int j = 0; j < 4; ++j) {
#pragma unroll
      for (int r = 0; r < 4; ++r) {
        int row = m0 + wrM + i * 16 + lg * 4 + r;
        int col = n0 + wcN + j * 16 + lr;
        float v = acc[i][j][r];
        if (EPI == 0) {
          int which = col >> 10, cc = col & 1023;
          int b = row >> 11, tt = row & 2047, h = cc >> 6, d = cc & 63;
          bf16* dst = Cb + (size_t)which * 8388608;
          dst[((size_t)((b << 4) + h) * TSEQ + tt) * HEAD_DIM + d] = (bf16)v;
        } else {
          size_t o = (size_t)row * N + col;
          float u = v + bias[col];
          Cb[o] = (bf16)(u > 0.f ? u : 0.f);
        }
      }
    }
  }
}

// ---------------- 256x128 GEMM + residual epilogue (fp32 out), 2-phase pipeline ----------
__global__ __launch_bounds__(512, 2) void gemm_res(
    const bf16* __restrict__ A, const bf16* __restrict__ BT,
    float* __restrict__ Cf, const float* __restrict__ bias,
    const float* __restrict__ resid, int M, int N, int K) {
  __shared__ __attribute__((aligned(16))) char lds[73728];  // 3 x 24KB
  int gx = gridDim.x;
  int nwg = gx * gridDim.y;
  int wgid = blockIdx.y * gx + blockIdx.x;
  int cpx = nwg >> 3;
  int swz = (wgid & 7) * cpx + (wgid >> 3);
  int m0 = (swz / gx) * 256, n0 = (swz % gx) * 128;
  int tid = threadIdx.x;
  int lane = tid & 63, wid = tid >> 6;
  int lr = lane & 15, lg = lane >> 4;
  int wrM = (wid >> 1) * 64;  // wave M base: 0/64/128/192
  int wcN = (wid & 1) * 64;   // wave N base: 0/64
  int crow = lane >> 2;
  int slotg = (lane & 3) ^ (crow & 3);
  int NT = K >> 5;
  size_t rb = (size_t)K * 2;

  auto stageA = [&](int t) {
    char* dst = lds + ((unsigned)t % 3u) * 24576u;
#pragma unroll
    for (int q = 0; q < 2; ++q) {
      int c = wid * 2 + q;  // chunk 0..15 (16 rows each)
      const char* srcA = (const char*)A + (size_t)(m0 + c * 16 + crow) * rb +
                         (size_t)t * 64 + slotg * 16;
      __builtin_amdgcn_global_load_lds((gvp)srcA, (svp)(dst + c * 1024), 16, 0,
                                       0);
    }
  };
  auto stageB = [&](int t) {
    char* dst = lds + ((unsigned)t % 3u) * 24576u + 16384u;
    const char* srcB = (const char*)BT + (size_t)(n0 + wid * 16 + crow) * rb +
                       (size_t)t * 64 + slotg * 16;
    __builtin_amdgcn_global_load_lds((gvp)srcB, (svp)(dst + wid * 1024), 16, 0,
                                     0);
  };

  stageA(0);
  stageB(0);
  stageA(1);
  stageB(1);
  f32x4 acc[4][4] = {};
  int swcol = ((lg ^ (lr & 3)) * 16);
  for (int t = 0; t < NT; ++t) {
    if (t == NT - 1)
      asm volatile("s_waitcnt vmcnt(0)" ::: "memory");
    else
      asm volatile("s_waitcnt vmcnt(3)" ::: "memory");
    __builtin_amdgcn_s_barrier();
    __builtin_amdgcn_sched_barrier(0);
    const char* Ab = lds + ((unsigned)t % 3u) * 24576u;
    const char* Bb = Ab + 16384;
    int tn = t + 2;
    bool st = tn < NT;
    // ---- phase A ----
    bf16x8 bfr[4], afA[2], afB[2];
#pragma unroll
    for (int j = 0; j < 4; ++j)
      bfr[j] = *(const bf16x8*)(Bb + (wcN + j * 16 + lr) * 64 + swcol);
#pragma unroll
    for (int i = 0; i < 2; ++i)
      afA[i] = *(const bf16x8*)(Ab + (wrM + i * 16 + lr) * 64 + swcol);
    if (st) stageA(tn);
    __builtin_amdgcn_s_barrier();
    __builtin_amdgcn_sched_barrier(0);
    __builtin_amdgcn_s_setprio(1);
#pragma unroll
    for (int i = 0; i < 2; ++i)
#pragma unroll
      for (int j = 0; j < 4; ++j)
        acc[i][j] = __builtin_amdgcn_mfma_f32_16x16x32_bf16(afA[i], bfr[j],
                                                            acc[i][j], 0, 0, 0);
    __builtin_amdgcn_s_setprio(0);
    __builtin_amdgcn_sched_barrier(0);
    // ---- phase B ----
#pragma unroll
    for (int i = 0; i < 2; ++i)
      afB[i] = *(const bf16x8*)(Ab + (wrM + 32 + i * 16 + lr) * 64 + swcol);
    if (st) stageB(tn);
    __builtin_amdgcn_s_barrier();
    __builtin_amdgcn_sched_barrier(0);
    __builtin_amdgcn_s_setprio(1);
#pragma unroll
    for (int i = 0; i < 2; ++i)
#pragma unroll
      for (int j = 0; j < 4; ++j)
        acc[2 + i][j] = __builtin_amdgcn_mfma_f32_16x16x32_bf16(
            afB[i], bfr[j], acc[2 + i][j], 0, 0, 0);
    __builtin_amdgcn_s_setprio(0);
    __builtin_amdgcn_sched_barrier(0);
  }
#pragma unroll
  for (int i = 0; i < 4; ++i) {
#pragma unroll
    for (int j = 0; j < 4; ++j) {
#pragma unroll
      for (int r = 0; r < 4; ++r) {
        int row = m0 + wrM + i * 16 + lg * 4 + r;
        int col = n0 + wcN + j * 16 + lr;
        size_t o = (size_t)row * N + col;
        Cf[o] = resid[o] + bias[col] + acc[i][j][r];
      }
    }
  }
}

// ---------------- causal flash attention: swapped-QK 32x32 MFMA, in-register P ----------
// QK^T computed as mfma_32x32x16(K_frag, Q_frag) => S^T: each lane owns ONE
// q-row (col = lane&31); softmax is lane-local (fixed-shift, deferred sum).
// P rebuilt as PV A-frags in-register: pack bf16 pairs + shfl_xor(32) half
// exchange (T12). No P LDS at all. grid (64,16) x 256 threads.
__global__ __launch_bounds__(256) void attn_kernel(
    const bf16* __restrict__ q, const bf16* __restrict__ k,
    const bf16* __restrict__ vt, bf16* __restrict__ out) {
  // Ks 8KB (64 keys x 64 d) | Vs 8KB (64 d x 64 keys), XOR-swizzled
  __shared__ __attribute__((aligned(16))) char ldsK[8192];
  __shared__ __attribute__((aligned(16))) char ldsV[8192];
  int bh = blockIdx.x;
  int b = bh >> 4, h = bh & 15;
  const bf16* qb = q + (size_t)bh * TSEQ * HEAD_DIM;
  const bf16* kb = k + (size_t)bh * TSEQ * HEAD_DIM;
  const bf16* vb = vt + (size_t)bh * HEAD_DIM * TSEQ;
  int tid = threadIdx.x, lane = tid & 63, w = tid >> 6;
  int l31 = lane & 31, hi = lane >> 5;
  int Q = 15 - blockIdx.y;    // supertile of 128 rows; longest job first
  int tw = Q * 128 + w * 32;  // wave's 32 q-rows
  int qrow = tw + l31;        // this lane's q-row (swapped layout)
  int srow0 = tid >> 3;       // staging rows 0..31 (i=0), +32 (i=1)
  int scol = (tid & 7) * 16;  // byte col
  int swz31 = (l31 & 7) << 4; // read-side swizzle for rows l31 / 32+l31
  // Q as B-frag (32x32x16): row = lane&31 = q, k = hi*8+e per 16-k slice
  bf16x8 aq[4];
#pragma unroll
  for (int f = 0; f < 4; ++f)
    aq[f] = *(const bf16x8*)&qb[(size_t)qrow * HEAD_DIM + f * 16 + hi * 8];
  f32x16 o0 = {}, o1 = {};
  float sacc = 0.f;
  int nj = 2 * Q + 2;
  for (int j = 0; j < nj; ++j) {
#pragma unroll
    for (int i = 0; i < 2; ++i) {
      int rr = srow0 + i * 32;
      int sw = scol ^ ((rr & 7) << 4);
      *(bf16x8*)(ldsK + rr * 128 + sw) =
          *(const bf16x8*)&kb[(size_t)(j * 64 + rr) * HEAD_DIM + (scol >> 1)];
      *(bf16x8*)(ldsV + rr * 128 + sw) =
          *(const bf16x8*)&vb[(size_t)rr * TSEQ + j * 64 + (scol >> 1)];
    }
    __syncthreads();
    // QK^T swapped: s = mfma(K, Q). s0 = keys 0..31, s1 = keys 32..63.
    f32x16 s0 = {}, s1 = {};
#pragma unroll
    for (int f = 0; f < 4; ++f) {
      int colb = (f * 32 + hi * 16) ^ swz31;
      bf16x8 ka = *(const bf16x8*)(ldsK + l31 * 128 + colb);
      bf16x8 kb2 = *(const bf16x8*)(ldsK + (32 + l31) * 128 + colb);
      s0 = __builtin_amdgcn_mfma_f32_32x32x16_bf16(ka, aq[f], s0, 0, 0, 0);
      s1 = __builtin_amdgcn_mfma_f32_32x32x16_bf16(kb2, aq[f], s1, 0, 0, 0);
    }
    if (j >= 2 * Q) {  // causal mask on boundary tiles
#pragma unroll
      for (int reg = 0; reg < 16; ++reg) {
        int key = j * 64 + (reg & 3) + 8 * (reg >> 2) + 4 * hi;
        if (key > qrow) s0[reg] = -1e30f;
        if (key + 32 > qrow) s1[reg] = -1e30f;
      }
    }
    // exp2 (fixed shift), deferred sum, pack to bf16 pairs
    unsigned pk0[8], pk1[8];
#pragma unroll
    for (int p = 0; p < 8; ++p) {
      float a0 = exp2f(s0[2 * p] - 8.f), b0 = exp2f(s0[2 * p + 1] - 8.f);
      float a1 = exp2f(s1[2 * p] - 8.f), b1 = exp2f(s1[2 * p + 1] - 8.f);
      sacc += (a0 + b0) + (a1 + b1);
      pk0[p] = pk2(a0, b0);
      pk1[p] = pk2(a1, b1);
    }
    // PV: pa[ks] A-frag (row=q=lane&31, k = key = ks*16 + hi*8 + e) built by
    // half-exchange: source hi = e>>2, source reg = (e&3)+8*(ks&1)+4*my_hi.
#pragma unroll
    for (int ks = 0; ks < 4; ++ks) {
      const unsigned* P = (ks >> 1) ? pk1 : pk0;
      int kp = (ks & 1) * 4;
      unsigned x0 = P[kp + 0], x1 = P[kp + 1];
      unsigned x2 = P[kp + 2], x3 = P[kp + 3];
      unsigned y0 = (unsigned)__shfl_xor((int)x0, 32);
      unsigned y1 = (unsigned)__shfl_xor((int)x1, 32);
      unsigned y2 = (unsigned)__shfl_xor((int)x2, 32);
      unsigned y3 = (unsigned)__shfl_xor((int)x3, 32);
      union { unsigned u[4]; bf16x8 v; } pa;
      pa.u[0] = hi ? y2 : x0;
      pa.u[1] = hi ? y3 : x1;
      pa.u[2] = hi ? x2 : y0;
      pa.u[3] = hi ? x3 : y1;
      int colb = (ks * 32 + hi * 16) ^ swz31;
      bf16x8 bv0 = *(const bf16x8*)(ldsV + l31 * 128 + colb);
      bf16x8 bv1 = *(const bf16x8*)(ldsV + (32 + l31) * 128 + colb);
      o0 = __builtin_amdgcn_mfma_f32_32x32x16_bf16(pa.v, bv0, o0, 0, 0, 0);
      o1 = __builtin_amdgcn_mfma_f32_32x32x16_bf16(pa.v, bv1, o1, 0, 0, 0);
    }
    __syncthreads();
  }
  // row-sum totals: own half + partner half; broadcast to output layout
  float tot = sacc + __shfl_xor(sacc, 32);
#pragma unroll
  for (int reg = 0; reg < 16; ++reg) {
    int ql = (reg & 3) + 8 * (reg >> 2) + 4 * hi;
    float lw = __shfl(tot, ql);
    float rl = 1.0f / lw;
    int t = tw + ql;
    size_t o = ((size_t)(b * TSEQ) + t) * EMBED + h * HEAD_DIM;
    out[o + l31] = (bf16)(o0[reg] * rl);
    out[o + 32 + l31] = (bf16)(o1[reg] * rl);
  }
}

// ---------------- launch ----------------
extern "C" void kernel_launch(void* const* d_in, const int* in_sizes, int n_in,
                              void* d_out, int out_size, void* d_ws,
                              size_t ws_size, hipStream_t stream) {
  const float* x = (const float*)d_in[0];
  const float* Wq = (const float*)d_in[1];
  const float* Wk = (const float*)d_in[2];
  const float* Wv = (const float*)d_in[3];
  const float* Wo = (const float*)d_in[4];
  const float* bo = (const float*)d_in[5];
  const float* W1 = (const float*)d_in[6];
  const float* b1 = (const float*)d_in[7];
  const float* W2 = (const float*)d_in[8];
  const float* b2 = (const float*)d_in[9];
  const float* g1 = (const float*)d_in[10];
  const float* be1 = (const float*)d_in[11];
  const float* g2 = (const float*)d_in[12];
  const float* be2 = (const float*)d_in[13];
  float* out = (float*)d_out;
  char* ws = (char*)d_ws;

  const size_t U = 16777216;  // 16 MiB
  bf16* h = (bf16*)(ws + 0 * U);
  bf16* qb = (bf16*)(ws + 1 * U);
  bf16* vtb = (bf16*)(ws + 0 * U);
  bf16* vnb = (bf16*)(ws + 3 * U);
  bf16* ao = (bf16*)(ws + 3 * U);
  float* x1 = (float*)(ws + 4 * U);
  bf16* h2 = (bf16*)(ws + 6 * U);
  bf16* ff1 = (bf16*)(ws + 0 * U);
  char* wbase = ws + 7 * U;
  bf16* WqkvT = (bf16*)(wbase);           // 6 MB
  bf16* WoT = (bf16*)(wbase + 6291456);   // 2 MB
  bf16* W1T = (bf16*)(wbase + 8388608);   // 8 MB
  bf16* W2T = (bf16*)(wbase + 16777216);  // 8 MB

  hipLaunchKernelGGL(conv_wqkv_t, dim3(16, 16, 3), dim3(256), 0, stream, Wq,
                     Wk, Wv, WqkvT);
  hipLaunchKernelGGL(transpose_conv, dim3(16, 16), dim3(256), 0, stream, Wo,
                     WoT, 1024, 1024);
  hipLaunchKernelGGL(transpose_conv, dim3(64, 16), dim3(256), 0, stream, W1,
                     W1T, 1024, 4096);
  hipLaunchKernelGGL(transpose_conv, dim3(16, 64), dim3(256), 0, stream, W2,
                     W2T, 4096, 1024);
  hipLaunchKernelGGL(ln_kernel, dim3(8192), dim3(256), 0, stream, x, g1, be1,
                     h);
  // fused QKV projection: 256x256 2-phase pipelined GEMM, scatter epilogue
  hipLaunchKernelGGL((gemm256<0>), dim3(12, 32), dim3(512), 0, stream, h,
                     WqkvT, qb, (const float*)nullptr, ROWS, 3072, 1024);
  // v [B,H,T,D] -> vt [B,H,D,T]
  hipLaunchKernelGGL(transpose_v, dim3(32, 64), dim3(256), 0, stream, vnb,
                     vtb);
  // attention (swapped-QK 32x32, in-register P, fixed-shift softmax)
  hipLaunchKernelGGL(attn_kernel, dim3(64, 16), dim3(256), 0, stream, qb,
                     qb + 8388608, vtb, ao);
  // x1 = x + ao @ Wo + bo : 256x128 pipelined GEMM with residual epilogue
  hipLaunchKernelGGL(gemm_res, dim3(8, 32), dim3(512), 0, stream, ao, WoT, x1,
                     bo, x, ROWS, 1024, 1024);
  // h2 = LN2(x1)
  hipLaunchKernelGGL(ln_kernel, dim3(8192), dim3(256), 0, stream, x1, g2, be2,
                     h2);
  // ff1 = relu(h2 @ W1 + b1): 256x256 2-phase pipelined GEMM
  hipLaunchKernelGGL((gemm256<3>), dim3(16, 32), dim3(512), 0, stream, h2, W1T,
                     ff1, b1, ROWS, 4096, 1024);
  // out = x1 + ff1 @ W2 + b2 : 256x128 pipelined GEMM with residual epilogue
  hipLaunchKernelGGL(gemm_res, dim3(8, 32), dim3(512), 0, stream, ff1, W2T,
                     out, b2, x1, ROWS, 1024, 4096);
}

// Round 13
// 390.329 us; speedup vs baseline: 1.2554x; 1.0216x over previous
//
#include <hip/hip_runtime.h>
#include <hip/hip_bf16.h>

#define EMBED 1024
#define HEADS 16
#define HEAD_DIM 64
#define FFDIM 4096
#define TSEQ 2048
#define BATCH 4
#define ROWS (BATCH * TSEQ)  // 8192

typedef __bf16 bf16;
typedef __attribute__((ext_vector_type(8))) __bf16 bf16x8;
typedef __attribute__((ext_vector_type(4))) __bf16 bf16x4;
typedef __attribute__((ext_vector_type(4))) float f32x4;
typedef __attribute__((ext_vector_type(16))) float f32x16;
typedef __attribute__((ext_vector_type(2))) unsigned u32x2;

typedef const __attribute__((address_space(1))) void* gvp;
typedef __attribute__((address_space(3))) void* svp;

__device__ inline unsigned pk2(float a, float b) {
  union { bf16 h[2]; unsigned u; } x;
  x.h[0] = (bf16)a;
  x.h[1] = (bf16)b;
  return x.u;
}

// ---------------- weight conversion (LDS-tiled transposes, coalesced) ----------------
__global__ __launch_bounds__(256) void conv_wqkv_t(
    const float* __restrict__ Wq, const float* __restrict__ Wk,
    const float* __restrict__ Wv, bf16* __restrict__ WqkvT) {
  __shared__ bf16 t[64][72];
  int tid = threadIdx.x;
  int k0 = blockIdx.x * 64;  // c-tile
  int head = blockIdx.y;
  int which = blockIdx.z;
  const float* src = which == 0 ? Wq : which == 1 ? Wk : Wv;
  float scale = which == 0 ? 0.125f * 1.44269504088896f : 1.0f;
  src += (size_t)head * 65536;
  bf16* dst = WqkvT + ((size_t)which * 1024 + head * 64) * 1024;
#pragma unroll
  for (int i = 0; i < 4; ++i) {
    int r = i * 16 + (tid >> 4);  // c within tile
    int c = (tid & 15) * 4;       // d
    float4 v = *(const float4*)&src[(size_t)(k0 + r) * 64 + c];
    t[c + 0][r] = (bf16)(v.x * scale);
    t[c + 1][r] = (bf16)(v.y * scale);
    t[c + 2][r] = (bf16)(v.z * scale);
    t[c + 3][r] = (bf16)(v.w * scale);
  }
  __syncthreads();
#pragma unroll
  for (int i = 0; i < 2; ++i) {
    int r = i * 32 + (tid >> 3);  // d row
    int c = (tid & 7) * 8;        // c col
    bf16x8 o;
#pragma unroll
    for (int j = 0; j < 8; ++j) o[j] = t[r][c + j];
    *(bf16x8*)&dst[(size_t)r * 1024 + k0 + c] = o;
  }
}

// W [K,N] fp32 -> WT [N,K] bf16, tiled 64x64
__global__ __launch_bounds__(256) void transpose_conv(
    const float* __restrict__ W, bf16* __restrict__ WT, int K, int N) {
  __shared__ bf16 t[64][72];
  int tid = threadIdx.x;
  int n0 = blockIdx.x * 64, k0 = blockIdx.y * 64;
#pragma unroll
  for (int i = 0; i < 4; ++i) {
    int r = i * 16 + (tid >> 4);  // k
    int c = (tid & 15) * 4;       // n
    float4 v = *(const float4*)&W[(size_t)(k0 + r) * N + n0 + c];
    t[c + 0][r] = (bf16)v.x;
    t[c + 1][r] = (bf16)v.y;
    t[c + 2][r] = (bf16)v.z;
    t[c + 3][r] = (bf16)v.w;
  }
  __syncthreads();
#pragma unroll
  for (int i = 0; i < 2; ++i) {
    int r = i * 32 + (tid >> 3);  // n
    int c = (tid & 7) * 8;        // k
    bf16x8 o;
#pragma unroll
    for (int j = 0; j < 8; ++j) o[j] = t[r][c + j];
    *(bf16x8*)&WT[(size_t)(n0 + r) * K + k0 + c] = o;
  }
}

// v [B,H,T,Dh] bf16 -> vt [B,H,Dh,T] bf16, per-bh 64x64 tiles
__global__ __launch_bounds__(256) void transpose_v(const bf16* __restrict__ v,
                                                   bf16* __restrict__ vt) {
  __shared__ bf16 t[64][72];
  int bh = blockIdx.y;
  int t0 = blockIdx.x * 64;
  const bf16* src = v + (size_t)bh * 131072;
  bf16* dst = vt + (size_t)bh * 131072;
  int tid = threadIdx.x;
#pragma unroll
  for (int i = 0; i < 2; ++i) {
    int c = tid + i * 256;
    int r = c >> 3, d0 = (c & 7) * 8;
    bf16x8 vv = *(const bf16x8*)&src[(size_t)(t0 + r) * 64 + d0];
#pragma unroll
    for (int j = 0; j < 8; ++j) t[d0 + j][r] = vv[j];
  }
  __syncthreads();
#pragma unroll
  for (int i = 0; i < 2; ++i) {
    int c = tid + i * 256;
    int r = c >> 3, s0 = (c & 7) * 8;
    bf16x8 o;
#pragma unroll
    for (int j = 0; j < 8; ++j) o[j] = t[r][s0 + j];
    *(bf16x8*)&dst[(size_t)r * 2048 + t0 + s0] = o;
  }
}

// ---------------- layernorm (fp32 in -> bf16 out) ----------------
__global__ __launch_bounds__(256) void ln_kernel(
    const float* __restrict__ x, const float* __restrict__ g,
    const float* __restrict__ bta, bf16* __restrict__ out) {
  int row = blockIdx.x;
  const float* xr = x + (size_t)row * EMBED;
  float4 v = ((const float4*)xr)[threadIdx.x];
  float s1 = v.x + v.y + v.z + v.w;
  float s2 = v.x * v.x + v.y * v.y + v.z * v.z + v.w * v.w;
#pragma unroll
  for (int off = 1; off < 64; off <<= 1) {
    s1 += __shfl_xor(s1, off);
    s2 += __shfl_xor(s2, off);
  }
  __shared__ float red[8];
  int wid = threadIdx.x >> 6;
  int lane = threadIdx.x & 63;
  if (lane == 0) {
    red[wid * 2] = s1;
    red[wid * 2 + 1] = s2;
  }
  __syncthreads();
  s1 = red[0] + red[2] + red[4] + red[6];
  s2 = red[1] + red[3] + red[5] + red[7];
  float mu = s1 * (1.0f / EMBED);
  float var = s2 * (1.0f / EMBED) - mu * mu;
  float rs = rsqrtf(var + 1e-5f);
  float4 gv = ((const float4*)g)[threadIdx.x];
  float4 bv = ((const float4*)bta)[threadIdx.x];
  bf16x4 o;
  o[0] = (bf16)((v.x - mu) * rs * gv.x + bv.x);
  o[1] = (bf16)((v.y - mu) * rs * gv.y + bv.y);
  o[2] = (bf16)((v.z - mu) * rs * gv.z + bv.z);
  o[3] = (bf16)((v.w - mu) * rs * gv.w + bv.w);
  *(bf16x4*)(out + (size_t)row * EMBED + threadIdx.x * 4) = o;
}

// ---------------- 256x256 GEMM, BK=32, 3 LDS buffers, 2-phase interleave ----------------
template <int EPI>
__global__ __launch_bounds__(512, 1) void gemm256(
    const bf16* __restrict__ A, const bf16* __restrict__ BT,
    bf16* __restrict__ Cb, const float* __restrict__ bias, int M, int N,
    int K) {
  __shared__ __attribute__((aligned(16))) char lds[98304];  // 3 x (A16K + B16K)
  int gx = gridDim.x;
  int nwg = gx * gridDim.y;
  int wgid = blockIdx.y * gx + blockIdx.x;
  int cpx = nwg >> 3;
  int swz = (wgid & 7) * cpx + (wgid >> 3);
  int m0 = (swz / gx) * 256, n0 = (swz % gx) * 256;
  int tid = threadIdx.x;
  int lane = tid & 63, wid = tid >> 6;
  int lr = lane & 15, lg = lane >> 4;
  int wrM = (wid >> 2) * 128;  // wave M base: 0 or 128
  int wcN = (wid & 3) * 64;    // wave N base: 0/64/128/192
  int crow = lane >> 2;        // staging row within 16-row chunk
  int slotg = (lane & 3) ^ (crow & 3);  // inverse-swizzled global 16B slot
  int NT = K >> 5;
  size_t rb = (size_t)K * 2;  // bytes per row of A / BT

  auto stageA = [&](int t) {
    char* dst = lds + ((unsigned)t % 3u) * 32768u;
#pragma unroll
    for (int q = 0; q < 2; ++q) {
      int c = wid * 2 + q;  // chunk 0..15 (16 rows each)
      const char* srcA = (const char*)A + (size_t)(m0 + c * 16 + crow) * rb +
                         (size_t)t * 64 + slotg * 16;
      __builtin_amdgcn_global_load_lds((gvp)srcA, (svp)(dst + c * 1024), 16, 0,
                                       0);
    }
  };
  auto stageB = [&](int t) {
    char* dst = lds + ((unsigned)t % 3u) * 32768u + 16384u;
#pragma unroll
    for (int q = 0; q < 2; ++q) {
      int c = wid * 2 + q;
      const char* srcB = (const char*)BT + (size_t)(n0 + c * 16 + crow) * rb +
                         (size_t)t * 64 + slotg * 16;
      __builtin_amdgcn_global_load_lds((gvp)srcB, (svp)(dst + c * 1024), 16, 0,
                                       0);
    }
  };

  stageA(0);
  stageB(0);
  stageA(1);
  stageB(1);
  f32x4 acc[8][4] = {};
  int swcol = ((lg ^ (lr & 3)) * 16);
  for (int t = 0; t < NT; ++t) {
    if (t == NT - 1)
      asm volatile("s_waitcnt vmcnt(0)" ::: "memory");
    else
      asm volatile("s_waitcnt vmcnt(4)" ::: "memory");
    __builtin_amdgcn_s_barrier();
    __builtin_amdgcn_sched_barrier(0);
    const char* Ab = lds + ((unsigned)t % 3u) * 32768u;
    const char* Bb = Ab + 16384;
    int tn = t + 2;
    bool st = tn < NT;
    // ---- phase A ----
    bf16x8 bfr[4], afA[4], afB[4];
#pragma unroll
    for (int j = 0; j < 4; ++j)
      bfr[j] = *(const bf16x8*)(Bb + (wcN + j * 16 + lr) * 64 + swcol);
#pragma unroll
    for (int i = 0; i < 4; ++i)
      afA[i] = *(const bf16x8*)(Ab + (wrM + i * 16 + lr) * 64 + swcol);
    if (st) stageA(tn);
    __builtin_amdgcn_s_barrier();
    __builtin_amdgcn_sched_barrier(0);
    __builtin_amdgcn_s_setprio(1);
#pragma unroll
    for (int i = 0; i < 4; ++i)
#pragma unroll
      for (int j = 0; j < 4; ++j)
        acc[i][j] = __builtin_amdgcn_mfma_f32_16x16x32_bf16(afA[i], bfr[j],
                                                            acc[i][j], 0, 0, 0);
    __builtin_amdgcn_s_setprio(0);
    __builtin_amdgcn_sched_barrier(0);
    // ---- phase B ----
#pragma unroll
    for (int i = 0; i < 4; ++i)
      afB[i] = *(const bf16x8*)(Ab + (wrM + 64 + i * 16 + lr) * 64 + swcol);
    if (st) stageB(tn);
    __builtin_amdgcn_s_barrier();
    __builtin_amdgcn_sched_barrier(0);
    __builtin_amdgcn_s_setprio(1);
#pragma unroll
    for (int i = 0; i < 4; ++i)
#pragma unroll
      for (int j = 0; j < 4; ++j)
        acc[4 + i][j] = __builtin_amdgcn_mfma_f32_16x16x32_bf16(
            afB[i], bfr[j], acc[4 + i][j], 0, 0, 0);
    __builtin_amdgcn_s_setprio(0);
    __builtin_amdgcn_sched_barrier(0);
  }
#pragma unroll
  for (int i = 0; i < 8; ++i) {
#pragma unroll
    for (int j = 0; j < 4; ++j) {
#pragma unroll
      for (int r = 0; r < 4; ++r) {
        int row = m0 + wrM + i * 16 + lg * 4 + r;
        int col = n0 + wcN + j * 16 + lr;
        float v = acc[i][j][r];
        if (EPI == 0) {
          int which = col >> 10, cc = col & 1023;
          int b = row >> 11, tt = row & 2047, h = cc >> 6, d = cc & 63;
          bf16* dst = Cb + (size_t)which * 8388608;
          dst[((size_t)((b << 4) + h) * TSEQ + tt) * HEAD_DIM + d] = (bf16)v;
        } else {
          size_t o = (size_t)row * N + col;
          float u = v + bias[col];
          Cb[o] = (bf16)(u > 0.f ? u : 0.f);
        }
      }
    }
  }
}

// ---------------- 256x128 GEMM + residual epilogue (fp32 out), 2-phase pipeline ----------
__global__ __launch_bounds__(512, 2) void gemm_res(
    const bf16* __restrict__ A, const bf16* __restrict__ BT,
    float* __restrict__ Cf, const float* __restrict__ bias,
    const float* __restrict__ resid, int M, int N, int K) {
  __shared__ __attribute__((aligned(16))) char lds[73728];  // 3 x 24KB
  int gx = gridDim.x;
  int nwg = gx * gridDim.y;
  int wgid = blockIdx.y * gx + blockIdx.x;
  int cpx = nwg >> 3;
  int swz = (wgid & 7) * cpx + (wgid >> 3);
  int m0 = (swz / gx) * 256, n0 = (swz % gx) * 128;
  int tid = threadIdx.x;
  int lane = tid & 63, wid = tid >> 6;
  int lr = lane & 15, lg = lane >> 4;
  int wrM = (wid >> 1) * 64;  // wave M base: 0/64/128/192
  int wcN = (wid & 1) * 64;   // wave N base: 0/64
  int crow = lane >> 2;
  int slotg = (lane & 3) ^ (crow & 3);
  int NT = K >> 5;
  size_t rb = (size_t)K * 2;

  auto stageA = [&](int t) {
    char* dst = lds + ((unsigned)t % 3u) * 24576u;
#pragma unroll
    for (int q = 0; q < 2; ++q) {
      int c = wid * 2 + q;  // chunk 0..15 (16 rows each)
      const char* srcA = (const char*)A + (size_t)(m0 + c * 16 + crow) * rb +
                         (size_t)t * 64 + slotg * 16;
      __builtin_amdgcn_global_load_lds((gvp)srcA, (svp)(dst + c * 1024), 16, 0,
                                       0);
    }
  };
  auto stageB = [&](int t) {
    char* dst = lds + ((unsigned)t % 3u) * 24576u + 16384u;
    const char* srcB = (const char*)BT + (size_t)(n0 + wid * 16 + crow) * rb +
                       (size_t)t * 64 + slotg * 16;
    __builtin_amdgcn_global_load_lds((gvp)srcB, (svp)(dst + wid * 1024), 16, 0,
                                     0);
  };

  stageA(0);
  stageB(0);
  stageA(1);
  stageB(1);
  f32x4 acc[4][4] = {};
  int swcol = ((lg ^ (lr & 3)) * 16);
  for (int t = 0; t < NT; ++t) {
    if (t == NT - 1)
      asm volatile("s_waitcnt vmcnt(0)" ::: "memory");
    else
      asm volatile("s_waitcnt vmcnt(3)" ::: "memory");
    __builtin_amdgcn_s_barrier();
    __builtin_amdgcn_sched_barrier(0);
    const char* Ab = lds + ((unsigned)t % 3u) * 24576u;
    const char* Bb = Ab + 16384;
    int tn = t + 2;
    bool st = tn < NT;
    // ---- phase A ----
    bf16x8 bfr[4], afA[2], afB[2];
#pragma unroll
    for (int j = 0; j < 4; ++j)
      bfr[j] = *(const bf16x8*)(Bb + (wcN + j * 16 + lr) * 64 + swcol);
#pragma unroll
    for (int i = 0; i < 2; ++i)
      afA[i] = *(const bf16x8*)(Ab + (wrM + i * 16 + lr) * 64 + swcol);
    if (st) stageA(tn);
    __builtin_amdgcn_s_barrier();
    __builtin_amdgcn_sched_barrier(0);
    __builtin_amdgcn_s_setprio(1);
#pragma unroll
    for (int i = 0; i < 2; ++i)
#pragma unroll
      for (int j = 0; j < 4; ++j)
        acc[i][j] = __builtin_amdgcn_mfma_f32_16x16x32_bf16(afA[i], bfr[j],
                                                            acc[i][j], 0, 0, 0);
    __builtin_amdgcn_s_setprio(0);
    __builtin_amdgcn_sched_barrier(0);
    // ---- phase B ----
#pragma unroll
    for (int i = 0; i < 2; ++i)
      afB[i] = *(const bf16x8*)(Ab + (wrM + 32 + i * 16 + lr) * 64 + swcol);
    if (st) stageB(tn);
    __builtin_amdgcn_s_barrier();
    __builtin_amdgcn_sched_barrier(0);
    __builtin_amdgcn_s_setprio(1);
#pragma unroll
    for (int i = 0; i < 2; ++i)
#pragma unroll
      for (int j = 0; j < 4; ++j)
        acc[2 + i][j] = __builtin_amdgcn_mfma_f32_16x16x32_bf16(
            afB[i], bfr[j], acc[2 + i][j], 0, 0, 0);
    __builtin_amdgcn_s_setprio(0);
    __builtin_amdgcn_sched_barrier(0);
  }
#pragma unroll
  for (int i = 0; i < 4; ++i) {
#pragma unroll
    for (int j = 0; j < 4; ++j) {
#pragma unroll
      for (int r = 0; r < 4; ++r) {
        int row = m0 + wrM + i * 16 + lg * 4 + r;
        int col = n0 + wcN + j * 16 + lr;
        size_t o = (size_t)row * N + col;
        Cf[o] = resid[o] + bias[col] + acc[i][j][r];
      }
    }
  }
}

// ---------------- causal flash attention: swapped-QK 32x32 MFMA, in-register P ----------
// QK^T computed as mfma_32x32x16(K_frag, Q_frag) => S^T: each lane owns ONE
// q-row. Softmax lane-local, fixed shift folded into MFMA C-init (-8).
// P->PV A-frags via permlane32_swap (VALU, no LDS crossbar). Fully-masked
// boundary tiles skipped per-wave. grid (64,16) x 256 threads.
__global__ __launch_bounds__(256) void attn_kernel(
    const bf16* __restrict__ q, const bf16* __restrict__ k,
    const bf16* __restrict__ vt, bf16* __restrict__ out) {
  __shared__ __attribute__((aligned(16))) char ldsK[8192];
  __shared__ __attribute__((aligned(16))) char ldsV[8192];
  int bh = blockIdx.x;
  int b = bh >> 4, h = bh & 15;
  const bf16* qb = q + (size_t)bh * TSEQ * HEAD_DIM;
  const bf16* kb = k + (size_t)bh * TSEQ * HEAD_DIM;
  const bf16* vb = vt + (size_t)bh * HEAD_DIM * TSEQ;
  int tid = threadIdx.x, lane = tid & 63, w = tid >> 6;
  int l31 = lane & 31, hi = lane >> 5;
  int Q = 15 - blockIdx.y;    // supertile of 128 rows; longest job first
  int tw = Q * 128 + w * 32;  // wave's 32 q-rows
  int qrow = tw + l31;        // this lane's q-row (swapped layout)
  int srow0 = tid >> 3;       // staging rows 0..31 (i=0), +32 (i=1)
  int scol = (tid & 7) * 16;  // byte col
  int swz31 = (l31 & 7) << 4; // read-side swizzle for rows l31 / 32+l31
  bf16x8 aq[4];
#pragma unroll
  for (int f = 0; f < 4; ++f)
    aq[f] = *(const bf16x8*)&qb[(size_t)qrow * HEAD_DIM + f * 16 + hi * 8];
  f32x16 o0 = {}, o1 = {};
  f32x16 minit;
#pragma unroll
  for (int i = 0; i < 16; ++i) minit[i] = -8.0f;  // softmax shift in C-init
  float sacc = 0.f;
  int nj = 2 * Q + 2;
  for (int j = 0; j < nj; ++j) {
#pragma unroll
    for (int i = 0; i < 2; ++i) {
      int rr = srow0 + i * 32;
      int sw = scol ^ ((rr & 7) << 4);
      *(bf16x8*)(ldsK + rr * 128 + sw) =
          *(const bf16x8*)&kb[(size_t)(j * 64 + rr) * HEAD_DIM + (scol >> 1)];
      *(bf16x8*)(ldsV + rr * 128 + sw) =
          *(const bf16x8*)&vb[(size_t)rr * TSEQ + j * 64 + (scol >> 1)];
    }
    __syncthreads();
    if (j * 64 <= tw + 31) {  // wave-uniform: skip fully-masked tiles
      // QK^T swapped: s = mfma(K, Q) with C-init = -8 (fixed shift folded in)
      f32x16 s0 = minit, s1 = minit;
#pragma unroll
      for (int f = 0; f < 4; ++f) {
        int colb = (f * 32 + hi * 16) ^ swz31;
        bf16x8 ka = *(const bf16x8*)(ldsK + l31 * 128 + colb);
        bf16x8 kb2 = *(const bf16x8*)(ldsK + (32 + l31) * 128 + colb);
        s0 = __builtin_amdgcn_mfma_f32_32x32x16_bf16(ka, aq[f], s0, 0, 0, 0);
        s1 = __builtin_amdgcn_mfma_f32_32x32x16_bf16(kb2, aq[f], s1, 0, 0, 0);
      }
      if (j >= 2 * Q) {  // causal mask on boundary tiles
#pragma unroll
        for (int reg = 0; reg < 16; ++reg) {
          int key = j * 64 + (reg & 3) + 8 * (reg >> 2) + 4 * hi;
          if (key > qrow) s0[reg] = -1e30f;
          if (key + 32 > qrow) s1[reg] = -1e30f;
        }
      }
      // exp2 (shift already applied), deferred sum, pack to bf16 pairs
      unsigned pk0[8], pk1[8];
#pragma unroll
      for (int p = 0; p < 8; ++p) {
        float a0 = exp2f(s0[2 * p]), b0 = exp2f(s0[2 * p + 1]);
        float a1 = exp2f(s1[2 * p]), b1 = exp2f(s1[2 * p + 1]);
        sacc += (a0 + b0) + (a1 + b1);
        pk0[p] = pk2(a0, b0);
        pk1[p] = pk2(a1, b1);
      }
      // PV: pa[ks] A-frag built by half-exchange.
      // (pa.u[0],pa.u[2]) = permlane32_swap(x0,x2): new_a=[a_lo|b_lo], new_b=[a_hi|b_hi]
#pragma unroll
      for (int ks = 0; ks < 4; ++ks) {
        const unsigned* P = (ks >> 1) ? pk1 : pk0;
        int kp = (ks & 1) * 4;
        union { unsigned u[4]; bf16x8 v; } pa;
#if __has_builtin(__builtin_amdgcn_permlane32_swap)
        u32x2 r02 = __builtin_amdgcn_permlane32_swap(P[kp + 0], P[kp + 2],
                                                     false, false);
        u32x2 r13 = __builtin_amdgcn_permlane32_swap(P[kp + 1], P[kp + 3],
                                                     false, false);
        pa.u[0] = r02.x;
        pa.u[2] = r02.y;
        pa.u[1] = r13.x;
        pa.u[3] = r13.y;
#else
        unsigned x0 = P[kp + 0], x1 = P[kp + 1];
        unsigned x2 = P[kp + 2], x3 = P[kp + 3];
        unsigned y0 = (unsigned)__shfl_xor((int)x0, 32);
        unsigned y1 = (unsigned)__shfl_xor((int)x1, 32);
        unsigned y2 = (unsigned)__shfl_xor((int)x2, 32);
        unsigned y3 = (unsigned)__shfl_xor((int)x3, 32);
        pa.u[0] = hi ? y2 : x0;
        pa.u[1] = hi ? y3 : x1;
        pa.u[2] = hi ? x2 : y0;
        pa.u[3] = hi ? x3 : y1;
#endif
        int colb = (ks * 32 + hi * 16) ^ swz31;
        bf16x8 bv0 = *(const bf16x8*)(ldsV + l31 * 128 + colb);
        bf16x8 bv1 = *(const bf16x8*)(ldsV + (32 + l31) * 128 + colb);
        o0 = __builtin_amdgcn_mfma_f32_32x32x16_bf16(pa.v, bv0, o0, 0, 0, 0);
        o1 = __builtin_amdgcn_mfma_f32_32x32x16_bf16(pa.v, bv1, o1, 0, 0, 0);
      }
    }
    __syncthreads();
  }
  // row-sum totals: own half + partner half; broadcast to output layout
  float tot = sacc + __shfl_xor(sacc, 32);
#pragma unroll
  for (int reg = 0; reg < 16; ++reg) {
    int ql = (reg & 3) + 8 * (reg >> 2) + 4 * hi;
    float lw = __shfl(tot, ql);
    float rl = 1.0f / lw;
    int t = tw + ql;
    size_t o = ((size_t)(b * TSEQ) + t) * EMBED + h * HEAD_DIM;
    out[o + l31] = (bf16)(o0[reg] * rl);
    out[o + 32 + l31] = (bf16)(o1[reg] * rl);
  }
}

// ---------------- launch ----------------
extern "C" void kernel_launch(void* const* d_in, const int* in_sizes, int n_in,
                              void* d_out, int out_size, void* d_ws,
                              size_t ws_size, hipStream_t stream) {
  const float* x = (const float*)d_in[0];
  const float* Wq = (const float*)d_in[1];
  const float* Wk = (const float*)d_in[2];
  const float* Wv = (const float*)d_in[3];
  const float* Wo = (const float*)d_in[4];
  const float* bo = (const float*)d_in[5];
  const float* W1 = (const float*)d_in[6];
  const float* b1 = (const float*)d_in[7];
  const float* W2 = (const float*)d_in[8];
  const float* b2 = (const float*)d_in[9];
  const float* g1 = (const float*)d_in[10];
  const float* be1 = (const float*)d_in[11];
  const float* g2 = (const float*)d_in[12];
  const float* be2 = (const float*)d_in[13];
  float* out = (float*)d_out;
  char* ws = (char*)d_ws;

  const size_t U = 16777216;  // 16 MiB
  bf16* h = (bf16*)(ws + 0 * U);
  bf16* qb = (bf16*)(ws + 1 * U);
  bf16* vtb = (bf16*)(ws + 0 * U);
  bf16* vnb = (bf16*)(ws + 3 * U);
  bf16* ao = (bf16*)(ws + 3 * U);
  float* x1 = (float*)(ws + 4 * U);
  bf16* h2 = (bf16*)(ws + 6 * U);
  bf16* ff1 = (bf16*)(ws + 0 * U);
  char* wbase = ws + 7 * U;
  bf16* WqkvT = (bf16*)(wbase);           // 6 MB
  bf16* WoT = (bf16*)(wbase + 6291456);   // 2 MB
  bf16* W1T = (bf16*)(wbase + 8388608);   // 8 MB
  bf16* W2T = (bf16*)(wbase + 16777216);  // 8 MB

  hipLaunchKernelGGL(conv_wqkv_t, dim3(16, 16, 3), dim3(256), 0, stream, Wq,
                     Wk, Wv, WqkvT);
  hipLaunchKernelGGL(transpose_conv, dim3(16, 16), dim3(256), 0, stream, Wo,
                     WoT, 1024, 1024);
  hipLaunchKernelGGL(transpose_conv, dim3(64, 16), dim3(256), 0, stream, W1,
                     W1T, 1024, 4096);
  hipLaunchKernelGGL(transpose_conv, dim3(16, 64), dim3(256), 0, stream, W2,
                     W2T, 4096, 1024);
  hipLaunchKernelGGL(ln_kernel, dim3(8192), dim3(256), 0, stream, x, g1, be1,
                     h);
  // fused QKV projection: 256x256 2-phase pipelined GEMM, scatter epilogue
  hipLaunchKernelGGL((gemm256<0>), dim3(12, 32), dim3(512), 0, stream, h,
                     WqkvT, qb, (const float*)nullptr, ROWS, 3072, 1024);
  // v [B,H,T,D] -> vt [B,H,D,T]
  hipLaunchKernelGGL(transpose_v, dim3(32, 64), dim3(256), 0, stream, vnb,
                     vtb);
  // attention (swapped-QK 32x32, in-register P, permlane half-exchange)
  hipLaunchKernelGGL(attn_kernel, dim3(64, 16), dim3(256), 0, stream, qb,
                     qb + 8388608, vtb, ao);
  // x1 = x + ao @ Wo + bo : 256x128 pipelined GEMM with residual epilogue
  hipLaunchKernelGGL(gemm_res, dim3(8, 32), dim3(512), 0, stream, ao, WoT, x1,
                     bo, x, ROWS, 1024, 1024);
  // h2 = LN2(x1)
  hipLaunchKernelGGL(ln_kernel, dim3(8192), dim3(256), 0, stream, x1, g2, be2,
                     h2);
  // ff1 = relu(h2 @ W1 + b1): 256x256 2-phase pipelined GEMM
  hipLaunchKernelGGL((gemm256<3>), dim3(16, 32), dim3(512), 0, stream, h2, W1T,
                     ff1, b1, ROWS, 4096, 1024);
  // out = x1 + ff1 @ W2 + b2 : 256x128 pipelined GEMM with residual epilogue
  hipLaunchKernelGGL(gemm_res, dim3(8, 32), dim3(512), 0, stream, ff1, W2T,
                     out, b2, x1, ROWS, 1024, 4096);
}

// Round 14
// 382.058 us; speedup vs baseline: 1.2826x; 1.0216x over previous
//
#include <hip/hip_runtime.h>
#include <hip/hip_bf16.h>

#define EMBED 1024
#define HEADS 16
#define HEAD_DIM 64
#define FFDIM 4096
#define TSEQ 2048
#define BATCH 4
#define ROWS (BATCH * TSEQ)  // 8192

typedef __bf16 bf16;
typedef __attribute__((ext_vector_type(8))) __bf16 bf16x8;
typedef __attribute__((ext_vector_type(4))) __bf16 bf16x4;
typedef __attribute__((ext_vector_type(4))) float f32x4;
typedef __attribute__((ext_vector_type(16))) float f32x16;
typedef __attribute__((ext_vector_type(2))) unsigned u32x2;

typedef const __attribute__((address_space(1))) void* gvp;
typedef __attribute__((address_space(3))) void* svp;

__device__ inline unsigned pk2(float a, float b) {
  union { bf16 h[2]; unsigned u; } x;
  x.h[0] = (bf16)a;
  x.h[1] = (bf16)b;
  return x.u;
}

// ---------------- weight conversion (LDS-tiled transposes, coalesced) ----------------
__global__ __launch_bounds__(256) void conv_wqkv_t(
    const float* __restrict__ Wq, const float* __restrict__ Wk,
    const float* __restrict__ Wv, bf16* __restrict__ WqkvT) {
  __shared__ bf16 t[64][72];
  int tid = threadIdx.x;
  int k0 = blockIdx.x * 64;  // c-tile
  int head = blockIdx.y;
  int which = blockIdx.z;
  const float* src = which == 0 ? Wq : which == 1 ? Wk : Wv;
  float scale = which == 0 ? 0.125f * 1.44269504088896f : 1.0f;
  src += (size_t)head * 65536;
  bf16* dst = WqkvT + ((size_t)which * 1024 + head * 64) * 1024;
#pragma unroll
  for (int i = 0; i < 4; ++i) {
    int r = i * 16 + (tid >> 4);  // c within tile
    int c = (tid & 15) * 4;       // d
    float4 v = *(const float4*)&src[(size_t)(k0 + r) * 64 + c];
    t[c + 0][r] = (bf16)(v.x * scale);
    t[c + 1][r] = (bf16)(v.y * scale);
    t[c + 2][r] = (bf16)(v.z * scale);
    t[c + 3][r] = (bf16)(v.w * scale);
  }
  __syncthreads();
#pragma unroll
  for (int i = 0; i < 2; ++i) {
    int r = i * 32 + (tid >> 3);  // d row
    int c = (tid & 7) * 8;        // c col
    bf16x8 o;
#pragma unroll
    for (int j = 0; j < 8; ++j) o[j] = t[r][c + j];
    *(bf16x8*)&dst[(size_t)r * 1024 + k0 + c] = o;
  }
}

// W [K,N] fp32 -> WT [N,K] bf16, tiled 64x64
__global__ __launch_bounds__(256) void transpose_conv(
    const float* __restrict__ W, bf16* __restrict__ WT, int K, int N) {
  __shared__ bf16 t[64][72];
  int tid = threadIdx.x;
  int n0 = blockIdx.x * 64, k0 = blockIdx.y * 64;
#pragma unroll
  for (int i = 0; i < 4; ++i) {
    int r = i * 16 + (tid >> 4);  // k
    int c = (tid & 15) * 4;       // n
    float4 v = *(const float4*)&W[(size_t)(k0 + r) * N + n0 + c];
    t[c + 0][r] = (bf16)v.x;
    t[c + 1][r] = (bf16)v.y;
    t[c + 2][r] = (bf16)v.z;
    t[c + 3][r] = (bf16)v.w;
  }
  __syncthreads();
#pragma unroll
  for (int i = 0; i < 2; ++i) {
    int r = i * 32 + (tid >> 3);  // n
    int c = (tid & 7) * 8;        // k
    bf16x8 o;
#pragma unroll
    for (int j = 0; j < 8; ++j) o[j] = t[r][c + j];
    *(bf16x8*)&WT[(size_t)(n0 + r) * K + k0 + c] = o;
  }
}

// v [B,H,T,Dh] bf16 -> vt [B,H,Dh,T] bf16, per-bh 64x64 tiles
__global__ __launch_bounds__(256) void transpose_v(const bf16* __restrict__ v,
                                                   bf16* __restrict__ vt) {
  __shared__ bf16 t[64][72];
  int bh = blockIdx.y;
  int t0 = blockIdx.x * 64;
  const bf16* src = v + (size_t)bh * 131072;
  bf16* dst = vt + (size_t)bh * 131072;
  int tid = threadIdx.x;
#pragma unroll
  for (int i = 0; i < 2; ++i) {
    int c = tid + i * 256;
    int r = c >> 3, d0 = (c & 7) * 8;
    bf16x8 vv = *(const bf16x8*)&src[(size_t)(t0 + r) * 64 + d0];
#pragma unroll
    for (int j = 0; j < 8; ++j) t[d0 + j][r] = vv[j];
  }
  __syncthreads();
#pragma unroll
  for (int i = 0; i < 2; ++i) {
    int c = tid + i * 256;
    int r = c >> 3, s0 = (c & 7) * 8;
    bf16x8 o;
#pragma unroll
    for (int j = 0; j < 8; ++j) o[j] = t[r][s0 + j];
    *(bf16x8*)&dst[(size_t)r * 2048 + t0 + s0] = o;
  }
}

// ---------------- layernorm (fp32 in -> bf16 out) ----------------
__global__ __launch_bounds__(256) void ln_kernel(
    const float* __restrict__ x, const float* __restrict__ g,
    const float* __restrict__ bta, bf16* __restrict__ out) {
  int row = blockIdx.x;
  const float* xr = x + (size_t)row * EMBED;
  float4 v = ((const float4*)xr)[threadIdx.x];
  float s1 = v.x + v.y + v.z + v.w;
  float s2 = v.x * v.x + v.y * v.y + v.z * v.z + v.w * v.w;
#pragma unroll
  for (int off = 1; off < 64; off <<= 1) {
    s1 += __shfl_xor(s1, off);
    s2 += __shfl_xor(s2, off);
  }
  __shared__ float red[8];
  int wid = threadIdx.x >> 6;
  int lane = threadIdx.x & 63;
  if (lane == 0) {
    red[wid * 2] = s1;
    red[wid * 2 + 1] = s2;
  }
  __syncthreads();
  s1 = red[0] + red[2] + red[4] + red[6];
  s2 = red[1] + red[3] + red[5] + red[7];
  float mu = s1 * (1.0f / EMBED);
  float var = s2 * (1.0f / EMBED) - mu * mu;
  float rs = rsqrtf(var + 1e-5f);
  float4 gv = ((const float4*)g)[threadIdx.x];
  float4 bv = ((const float4*)bta)[threadIdx.x];
  bf16x4 o;
  o[0] = (bf16)((v.x - mu) * rs * gv.x + bv.x);
  o[1] = (bf16)((v.y - mu) * rs * gv.y + bv.y);
  o[2] = (bf16)((v.z - mu) * rs * gv.z + bv.z);
  o[3] = (bf16)((v.w - mu) * rs * gv.w + bv.w);
  *(bf16x4*)(out + (size_t)row * EMBED + threadIdx.x * 4) = o;
}

// ---------------- 256x256 GEMM, BK=32, 3 LDS buffers, 2-phase interleave ----------------
// LDS swizzle: slot ^= (row>>1)&3 -> ds_read_b128 bank-group = 4*(row&1) +
// lg^((row>>1)&3), distinct for all 8 row-residues => 2 lanes/group (free).
template <int EPI>
__global__ __launch_bounds__(512, 1) void gemm256(
    const bf16* __restrict__ A, const bf16* __restrict__ BT,
    bf16* __restrict__ Cb, const float* __restrict__ bias, int M, int N,
    int K) {
  __shared__ __attribute__((aligned(16))) char lds[98304];  // 3 x (A16K + B16K)
  int gx = gridDim.x;
  int nwg = gx * gridDim.y;
  int wgid = blockIdx.y * gx + blockIdx.x;
  int cpx = nwg >> 3;
  int swz = (wgid & 7) * cpx + (wgid >> 3);
  int m0 = (swz / gx) * 256, n0 = (swz % gx) * 256;
  int tid = threadIdx.x;
  int lane = tid & 63, wid = tid >> 6;
  int lr = lane & 15, lg = lane >> 4;
  int wrM = (wid >> 2) * 128;  // wave M base: 0 or 128
  int wcN = (wid & 3) * 64;    // wave N base: 0/64/128/192
  int crow = lane >> 2;        // staging row within 16-row chunk
  int slotg = (lane & 3) ^ ((crow >> 1) & 3);  // inverse-swizzled global slot
  int NT = K >> 5;
  size_t rb = (size_t)K * 2;  // bytes per row of A / BT

  auto stageA = [&](int t) {
    char* dst = lds + ((unsigned)t % 3u) * 32768u;
#pragma unroll
    for (int q = 0; q < 2; ++q) {
      int c = wid * 2 + q;  // chunk 0..15 (16 rows each)
      const char* srcA = (const char*)A + (size_t)(m0 + c * 16 + crow) * rb +
                         (size_t)t * 64 + slotg * 16;
      __builtin_amdgcn_global_load_lds((gvp)srcA, (svp)(dst + c * 1024), 16, 0,
                                       0);
    }
  };
  auto stageB = [&](int t) {
    char* dst = lds + ((unsigned)t % 3u) * 32768u + 16384u;
#pragma unroll
    for (int q = 0; q < 2; ++q) {
      int c = wid * 2 + q;
      const char* srcB = (const char*)BT + (size_t)(n0 + c * 16 + crow) * rb +
                         (size_t)t * 64 + slotg * 16;
      __builtin_amdgcn_global_load_lds((gvp)srcB, (svp)(dst + c * 1024), 16, 0,
                                       0);
    }
  };

  stageA(0);
  stageB(0);
  stageA(1);
  stageB(1);
  f32x4 acc[8][4] = {};
  int swcol = ((lg ^ ((lr >> 1) & 3)) * 16);
  for (int t = 0; t < NT; ++t) {
    if (t == NT - 1)
      asm volatile("s_waitcnt vmcnt(0)" ::: "memory");
    else
      asm volatile("s_waitcnt vmcnt(4)" ::: "memory");
    __builtin_amdgcn_s_barrier();
    __builtin_amdgcn_sched_barrier(0);
    const char* Ab = lds + ((unsigned)t % 3u) * 32768u;
    const char* Bb = Ab + 16384;
    int tn = t + 2;
    bool st = tn < NT;
    // ---- phase A ----
    bf16x8 bfr[4], afA[4], afB[4];
#pragma unroll
    for (int j = 0; j < 4; ++j)
      bfr[j] = *(const bf16x8*)(Bb + (wcN + j * 16 + lr) * 64 + swcol);
#pragma unroll
    for (int i = 0; i < 4; ++i)
      afA[i] = *(const bf16x8*)(Ab + (wrM + i * 16 + lr) * 64 + swcol);
    if (st) stageA(tn);
    __builtin_amdgcn_s_barrier();
    __builtin_amdgcn_sched_barrier(0);
    __builtin_amdgcn_s_setprio(1);
#pragma unroll
    for (int i = 0; i < 4; ++i)
#pragma unroll
      for (int j = 0; j < 4; ++j)
        acc[i][j] = __builtin_amdgcn_mfma_f32_16x16x32_bf16(afA[i], bfr[j],
                                                            acc[i][j], 0, 0, 0);
    __builtin_amdgcn_s_setprio(0);
    __builtin_amdgcn_sched_barrier(0);
    // ---- phase B ----
#pragma unroll
    for (int i = 0; i < 4; ++i)
      afB[i] = *(const bf16x8*)(Ab + (wrM + 64 + i * 16 + lr) * 64 + swcol);
    if (st) stageB(tn);
    __builtin_amdgcn_s_barrier();
    __builtin_amdgcn_sched_barrier(0);
    __builtin_amdgcn_s_setprio(1);
#pragma unroll
    for (int i = 0; i < 4; ++i)
#pragma unroll
      for (int j = 0; j < 4; ++j)
        acc[4 + i][j] = __builtin_amdgcn_mfma_f32_16x16x32_bf16(
            afB[i], bfr[j], acc[4 + i][j], 0, 0, 0);
    __builtin_amdgcn_s_setprio(0);
    __builtin_amdgcn_sched_barrier(0);
  }
#pragma unroll
  for (int i = 0; i < 8; ++i) {
#pragma unroll
    for (int j = 0; j < 4; ++j) {
#pragma unroll
      for (int r = 0; r < 4; ++r) {
        int row = m0 + wrM + i * 16 + lg * 4 + r;
        int col = n0 + wcN + j * 16 + lr;
        float v = acc[i][j][r];
        if (EPI == 0) {
          int which = col >> 10, cc = col & 1023;
          int b = row >> 11, tt = row & 2047, h = cc >> 6, d = cc & 63;
          bf16* dst = Cb + (size_t)which * 8388608;
          dst[((size_t)((b << 4) + h) * TSEQ + tt) * HEAD_DIM + d] = (bf16)v;
        } else {
          size_t o = (size_t)row * N + col;
          float u = v + bias[col];
          Cb[o] = (bf16)(u > 0.f ? u : 0.f);
        }
      }
    }
  }
}

// ---------------- 256x128 GEMM + residual epilogue (fp32 out), 2-phase pipeline ----------
__global__ __launch_bounds__(512, 2) void gemm_res(
    const bf16* __restrict__ A, const bf16* __restrict__ BT,
    float* __restrict__ Cf, const float* __restrict__ bias,
    const float* __restrict__ resid, int M, int N, int K) {
  __shared__ __attribute__((aligned(16))) char lds[73728];  // 3 x 24KB
  int gx = gridDim.x;
  int nwg = gx * gridDim.y;
  int wgid = blockIdx.y * gx + blockIdx.x;
  int cpx = nwg >> 3;
  int swz = (wgid & 7) * cpx + (wgid >> 3);
  int m0 = (swz / gx) * 256, n0 = (swz % gx) * 128;
  int tid = threadIdx.x;
  int lane = tid & 63, wid = tid >> 6;
  int lr = lane & 15, lg = lane >> 4;
  int wrM = (wid >> 1) * 64;  // wave M base: 0/64/128/192
  int wcN = (wid & 1) * 64;   // wave N base: 0/64
  int crow = lane >> 2;
  int slotg = (lane & 3) ^ ((crow >> 1) & 3);
  int NT = K >> 5;
  size_t rb = (size_t)K * 2;

  auto stageA = [&](int t) {
    char* dst = lds + ((unsigned)t % 3u) * 24576u;
#pragma unroll
    for (int q = 0; q < 2; ++q) {
      int c = wid * 2 + q;  // chunk 0..15 (16 rows each)
      const char* srcA = (const char*)A + (size_t)(m0 + c * 16 + crow) * rb +
                         (size_t)t * 64 + slotg * 16;
      __builtin_amdgcn_global_load_lds((gvp)srcA, (svp)(dst + c * 1024), 16, 0,
                                       0);
    }
  };
  auto stageB = [&](int t) {
    char* dst = lds + ((unsigned)t % 3u) * 24576u + 16384u;
    const char* srcB = (const char*)BT + (size_t)(n0 + wid * 16 + crow) * rb +
                       (size_t)t * 64 + slotg * 16;
    __builtin_amdgcn_global_load_lds((gvp)srcB, (svp)(dst + wid * 1024), 16, 0,
                                     0);
  };

  stageA(0);
  stageB(0);
  stageA(1);
  stageB(1);
  f32x4 acc[4][4] = {};
  int swcol = ((lg ^ ((lr >> 1) & 3)) * 16);
  for (int t = 0; t < NT; ++t) {
    if (t == NT - 1)
      asm volatile("s_waitcnt vmcnt(0)" ::: "memory");
    else
      asm volatile("s_waitcnt vmcnt(3)" ::: "memory");
    __builtin_amdgcn_s_barrier();
    __builtin_amdgcn_sched_barrier(0);
    const char* Ab = lds + ((unsigned)t % 3u) * 24576u;
    const char* Bb = Ab + 16384;
    int tn = t + 2;
    bool st = tn < NT;
    // ---- phase A ----
    bf16x8 bfr[4], afA[2], afB[2];
#pragma unroll
    for (int j = 0; j < 4; ++j)
      bfr[j] = *(const bf16x8*)(Bb + (wcN + j * 16 + lr) * 64 + swcol);
#pragma unroll
    for (int i = 0; i < 2; ++i)
      afA[i] = *(const bf16x8*)(Ab + (wrM + i * 16 + lr) * 64 + swcol);
    if (st) stageA(tn);
    __builtin_amdgcn_s_barrier();
    __builtin_amdgcn_sched_barrier(0);
    __builtin_amdgcn_s_setprio(1);
#pragma unroll
    for (int i = 0; i < 2; ++i)
#pragma unroll
      for (int j = 0; j < 4; ++j)
        acc[i][j] = __builtin_amdgcn_mfma_f32_16x16x32_bf16(afA[i], bfr[j],
                                                            acc[i][j], 0, 0, 0);
    __builtin_amdgcn_s_setprio(0);
    __builtin_amdgcn_sched_barrier(0);
    // ---- phase B ----
#pragma unroll
    for (int i = 0; i < 2; ++i)
      afB[i] = *(const bf16x8*)(Ab + (wrM + 32 + i * 16 + lr) * 64 + swcol);
    if (st) stageB(tn);
    __builtin_amdgcn_s_barrier();
    __builtin_amdgcn_sched_barrier(0);
    __builtin_amdgcn_s_setprio(1);
#pragma unroll
    for (int i = 0; i < 2; ++i)
#pragma unroll
      for (int j = 0; j < 4; ++j)
        acc[2 + i][j] = __builtin_amdgcn_mfma_f32_16x16x32_bf16(
            afB[i], bfr[j], acc[2 + i][j], 0, 0, 0);
    __builtin_amdgcn_s_setprio(0);
    __builtin_amdgcn_sched_barrier(0);
  }
#pragma unroll
  for (int i = 0; i < 4; ++i) {
#pragma unroll
    for (int j = 0; j < 4; ++j) {
#pragma unroll
      for (int r = 0; r < 4; ++r) {
        int row = m0 + wrM + i * 16 + lg * 4 + r;
        int col = n0 + wcN + j * 16 + lr;
        size_t o = (size_t)row * N + col;
        Cf[o] = resid[o] + bias[col] + acc[i][j][r];
      }
    }
  }
}

// ---------------- causal flash attention: swapped-QK 32x32 MFMA, in-register P ----------
__global__ __launch_bounds__(256) void attn_kernel(
    const bf16* __restrict__ q, const bf16* __restrict__ k,
    const bf16* __restrict__ vt, bf16* __restrict__ out) {
  __shared__ __attribute__((aligned(16))) char ldsK[8192];
  __shared__ __attribute__((aligned(16))) char ldsV[8192];
  int bh = blockIdx.x;
  int b = bh >> 4, h = bh & 15;
  const bf16* qb = q + (size_t)bh * TSEQ * HEAD_DIM;
  const bf16* kb = k + (size_t)bh * TSEQ * HEAD_DIM;
  const bf16* vb = vt + (size_t)bh * HEAD_DIM * TSEQ;
  int tid = threadIdx.x, lane = tid & 63, w = tid >> 6;
  int l31 = lane & 31, hi = lane >> 5;
  int Q = 15 - blockIdx.y;    // supertile of 128 rows; longest job first
  int tw = Q * 128 + w * 32;  // wave's 32 q-rows
  int qrow = tw + l31;        // this lane's q-row (swapped layout)
  int srow0 = tid >> 3;       // staging rows 0..31 (i=0), +32 (i=1)
  int scol = (tid & 7) * 16;  // byte col
  int swz31 = (l31 & 7) << 4; // read-side swizzle for rows l31 / 32+l31
  bf16x8 aq[4];
#pragma unroll
  for (int f = 0; f < 4; ++f)
    aq[f] = *(const bf16x8*)&qb[(size_t)qrow * HEAD_DIM + f * 16 + hi * 8];
  f32x16 o0 = {}, o1 = {};
  f32x16 minit;
#pragma unroll
  for (int i = 0; i < 16; ++i) minit[i] = -8.0f;  // softmax shift in C-init
  float sacc = 0.f;
  int nj = 2 * Q + 2;
  for (int j = 0; j < nj; ++j) {
#pragma unroll
    for (int i = 0; i < 2; ++i) {
      int rr = srow0 + i * 32;
      int sw = scol ^ ((rr & 7) << 4);
      *(bf16x8*)(ldsK + rr * 128 + sw) =
          *(const bf16x8*)&kb[(size_t)(j * 64 + rr) * HEAD_DIM + (scol >> 1)];
      *(bf16x8*)(ldsV + rr * 128 + sw) =
          *(const bf16x8*)&vb[(size_t)rr * TSEQ + j * 64 + (scol >> 1)];
    }
    __syncthreads();
    if (j * 64 <= tw + 31) {  // wave-uniform: skip fully-masked tiles
      f32x16 s0 = minit, s1 = minit;
#pragma unroll
      for (int f = 0; f < 4; ++f) {
        int colb = (f * 32 + hi * 16) ^ swz31;
        bf16x8 ka = *(const bf16x8*)(ldsK + l31 * 128 + colb);
        bf16x8 kb2 = *(const bf16x8*)(ldsK + (32 + l31) * 128 + colb);
        s0 = __builtin_amdgcn_mfma_f32_32x32x16_bf16(ka, aq[f], s0, 0, 0, 0);
        s1 = __builtin_amdgcn_mfma_f32_32x32x16_bf16(kb2, aq[f], s1, 0, 0, 0);
      }
      if (j >= 2 * Q) {  // causal mask on boundary tiles
#pragma unroll
        for (int reg = 0; reg < 16; ++reg) {
          int key = j * 64 + (reg & 3) + 8 * (reg >> 2) + 4 * hi;
          if (key > qrow) s0[reg] = -1e30f;
          if (key + 32 > qrow) s1[reg] = -1e30f;
        }
      }
      unsigned pk0[8], pk1[8];
#pragma unroll
      for (int p = 0; p < 8; ++p) {
        float a0 = exp2f(s0[2 * p]), b0 = exp2f(s0[2 * p + 1]);
        float a1 = exp2f(s1[2 * p]), b1 = exp2f(s1[2 * p + 1]);
        sacc += (a0 + b0) + (a1 + b1);
        pk0[p] = pk2(a0, b0);
        pk1[p] = pk2(a1, b1);
      }
#pragma unroll
      for (int ks = 0; ks < 4; ++ks) {
        const unsigned* P = (ks >> 1) ? pk1 : pk0;
        int kp = (ks & 1) * 4;
        union { unsigned u[4]; bf16x8 v; } pa;
#if __has_builtin(__builtin_amdgcn_permlane32_swap)
        u32x2 r02 = __builtin_amdgcn_permlane32_swap(P[kp + 0], P[kp + 2],
                                                     false, false);
        u32x2 r13 = __builtin_amdgcn_permlane32_swap(P[kp + 1], P[kp + 3],
                                                     false, false);
        pa.u[0] = r02.x;
        pa.u[2] = r02.y;
        pa.u[1] = r13.x;
        pa.u[3] = r13.y;
#else
        unsigned x0 = P[kp + 0], x1 = P[kp + 1];
        unsigned x2 = P[kp + 2], x3 = P[kp + 3];
        unsigned y0 = (unsigned)__shfl_xor((int)x0, 32);
        unsigned y1 = (unsigned)__shfl_xor((int)x1, 32);
        unsigned y2 = (unsigned)__shfl_xor((int)x2, 32);
        unsigned y3 = (unsigned)__shfl_xor((int)x3, 32);
        pa.u[0] = hi ? y2 : x0;
        pa.u[1] = hi ? y3 : x1;
        pa.u[2] = hi ? x2 : y0;
        pa.u[3] = hi ? x3 : y1;
#endif
        int colb = (ks * 32 + hi * 16) ^ swz31;
        bf16x8 bv0 = *(const bf16x8*)(ldsV + l31 * 128 + colb);
        bf16x8 bv1 = *(const bf16x8*)(ldsV + (32 + l31) * 128 + colb);
        o0 = __builtin_amdgcn_mfma_f32_32x32x16_bf16(pa.v, bv0, o0, 0, 0, 0);
        o1 = __builtin_amdgcn_mfma_f32_32x32x16_bf16(pa.v, bv1, o1, 0, 0, 0);
      }
    }
    __syncthreads();
  }
  float tot = sacc + __shfl_xor(sacc, 32);
#pragma unroll
  for (int reg = 0; reg < 16; ++reg) {
    int ql = (reg & 3) + 8 * (reg >> 2) + 4 * hi;
    float lw = __shfl(tot, ql);
    float rl = 1.0f / lw;
    int t = tw + ql;
    size_t o = ((size_t)(b * TSEQ) + t) * EMBED + h * HEAD_DIM;
    out[o + l31] = (bf16)(o0[reg] * rl);
    out[o + 32 + l31] = (bf16)(o1[reg] * rl);
  }
}

// ---------------- launch ----------------
extern "C" void kernel_launch(void* const* d_in, const int* in_sizes, int n_in,
                              void* d_out, int out_size, void* d_ws,
                              size_t ws_size, hipStream_t stream) {
  const float* x = (const float*)d_in[0];
  const float* Wq = (const float*)d_in[1];
  const float* Wk = (const float*)d_in[2];
  const float* Wv = (const float*)d_in[3];
  const float* Wo = (const float*)d_in[4];
  const float* bo = (const float*)d_in[5];
  const float* W1 = (const float*)d_in[6];
  const float* b1 = (const float*)d_in[7];
  const float* W2 = (const float*)d_in[8];
  const float* b2 = (const float*)d_in[9];
  const float* g1 = (const float*)d_in[10];
  const float* be1 = (const float*)d_in[11];
  const float* g2 = (const float*)d_in[12];
  const float* be2 = (const float*)d_in[13];
  float* out = (float*)d_out;
  char* ws = (char*)d_ws;

  const size_t U = 16777216;  // 16 MiB
  bf16* h = (bf16*)(ws + 0 * U);
  bf16* qb = (bf16*)(ws + 1 * U);
  bf16* vtb = (bf16*)(ws + 0 * U);
  bf16* vnb = (bf16*)(ws + 3 * U);
  bf16* ao = (bf16*)(ws + 3 * U);
  float* x1 = (float*)(ws + 4 * U);
  bf16* h2 = (bf16*)(ws + 6 * U);
  bf16* ff1 = (bf16*)(ws + 0 * U);
  char* wbase = ws + 7 * U;
  bf16* WqkvT = (bf16*)(wbase);           // 6 MB
  bf16* WoT = (bf16*)(wbase + 6291456);   // 2 MB
  bf16* W1T = (bf16*)(wbase + 8388608);   // 8 MB
  bf16* W2T = (bf16*)(wbase + 16777216);  // 8 MB

  hipLaunchKernelGGL(conv_wqkv_t, dim3(16, 16, 3), dim3(256), 0, stream, Wq,
                     Wk, Wv, WqkvT);
  hipLaunchKernelGGL(transpose_conv, dim3(16, 16), dim3(256), 0, stream, Wo,
                     WoT, 1024, 1024);
  hipLaunchKernelGGL(transpose_conv, dim3(64, 16), dim3(256), 0, stream, W1,
                     W1T, 1024, 4096);
  hipLaunchKernelGGL(transpose_conv, dim3(16, 64), dim3(256), 0, stream, W2,
                     W2T, 4096, 1024);
  hipLaunchKernelGGL(ln_kernel, dim3(8192), dim3(256), 0, stream, x, g1, be1,
                     h);
  // fused QKV projection: 256x256 2-phase pipelined GEMM, scatter epilogue
  hipLaunchKernelGGL((gemm256<0>), dim3(12, 32), dim3(512), 0, stream, h,
                     WqkvT, qb, (const float*)nullptr, ROWS, 3072, 1024);
  // v [B,H,T,D] -> vt [B,H,D,T]
  hipLaunchKernelGGL(transpose_v, dim3(32, 64), dim3(256), 0, stream, vnb,
                     vtb);
  // attention (swapped-QK 32x32, in-register P, permlane half-exchange)
  hipLaunchKernelGGL(attn_kernel, dim3(64, 16), dim3(256), 0, stream, qb,
                     qb + 8388608, vtb, ao);
  // x1 = x + ao @ Wo + bo : 256x128 pipelined GEMM with residual epilogue
  hipLaunchKernelGGL(gemm_res, dim3(8, 32), dim3(512), 0, stream, ao, WoT, x1,
                     bo, x, ROWS, 1024, 1024);
  // h2 = LN2(x1)
  hipLaunchKernelGGL(ln_kernel, dim3(8192), dim3(256), 0, stream, x1, g2, be2,
                     h2);
  // ff1 = relu(h2 @ W1 + b1): 256x256 2-phase pipelined GEMM
  hipLaunchKernelGGL((gemm256<3>), dim3(16, 32), dim3(512), 0, stream, h2, W1T,
                     ff1, b1, ROWS, 4096, 1024);
  // out = x1 + ff1 @ W2 + b2 : 256x128 pipelined GEMM with residual epilogue
  hipLaunchKernelGGL(gemm_res, dim3(8, 32), dim3(512), 0, stream, ff1, W2T,
                     out, b2, x1, ROWS, 1024, 4096);
}